// Round 23
// baseline (319.808 us; speedup 1.0000x reference)
//
#include <hip/hip_runtime.h>
#include <stdint.h>

typedef __attribute__((ext_vector_type(8))) short short8;
typedef __attribute__((ext_vector_type(4))) float f32x4;

__device__ __forceinline__ unsigned short f2b(float f) {
  union { float f; uint32_t u; } v; v.f = f;
  uint32_t r = (v.u + 0x7fffu + ((v.u >> 16) & 1u)) >> 16;
  return (unsigned short)r;
}
__device__ __forceinline__ float b2f(unsigned short h) {
  union { uint32_t u; float f; } v; v.u = ((uint32_t)h) << 16; return v.f;
}

__device__ __forceinline__ void load_lds16(const void* g, void* l) {
  __builtin_amdgcn_global_load_lds(
      (const __attribute__((address_space(1))) uint32_t*)g,
      (__attribute__((address_space(3))) uint32_t*)l, 16, 0, 0);
}

__device__ __forceinline__ float elu1(float v) {
  return v > 0.f ? v : expf(v) - 1.f;
}

// ------------- merged prep: cvt (x_p,x_a->bf16) || 5x transpose+cast || hist3 -------------
#define NB_CVT 1024
#define NB_T 320
#define NB_H 256
__global__ void prep_all(
    const float4* __restrict__ xp_in, ushort4* __restrict__ xp_out, int n4p,
    const float4* __restrict__ xa_in, ushort4* __restrict__ xa_out, int n4a,
    const float* __restrict__ W0, const float* __restrict__ W1,
    const float* __restrict__ W2, const float* __restrict__ W3,
    const float* __restrict__ W4,
    unsigned short* __restrict__ T0, unsigned short* __restrict__ T1,
    unsigned short* __restrict__ T2, unsigned short* __restrict__ T3,
    unsigned short* __restrict__ T4,
    const int* __restrict__ d1, int E1, int* __restrict__ c1,
    const int* __restrict__ d2, int E2, int* __restrict__ c2,
    const int* __restrict__ d3, int E3, int* __restrict__ c3) {
  __shared__ unsigned short t[32][33];
  const int bid = blockIdx.x;
  if (bid < NB_CVT) {
    int i = bid * blockDim.x + threadIdx.x;
    int stride = NB_CVT * blockDim.x;
    int tot = n4p + n4a;
    for (; i < tot; i += stride) {
      const float4 f = (i < n4p) ? xp_in[i] : xa_in[i - n4p];
      ushort4 o;
      o.x = f2b(f.x); o.y = f2b(f.y); o.z = f2b(f.z); o.w = f2b(f.w);
      if (i < n4p) xp_out[i] = o;
      else xa_out[i - n4p] = o;
    }
  } else if (bid < NB_CVT + NB_T) {
    int local = bid - NB_CVT;
    int mat = local >> 6, bt = local & 63;
    const float* W; unsigned short* T;
    switch (mat) {
      case 0: W = W0; T = T0; break;
      case 1: W = W1; T = T1; break;
      case 2: W = W2; T = T2; break;
      case 3: W = W3; T = T3; break;
      default: W = W4; T = T4; break;
    }
    int bx = bt & 7, by = bt >> 3;
    int x = threadIdx.x & 31, y = threadIdx.x >> 5;  // 32x8
    for (int i = 0; i < 32; i += 8)
      t[y + i][x] = f2b(W[(by * 32 + y + i) * 256 + bx * 32 + x]);
    __syncthreads();
    for (int i = 0; i < 32; i += 8)
      T[(bx * 32 + y + i) * 256 + by * 32 + x] = t[x][y + i];
  } else {
    int local = bid - NB_CVT - NB_T;
    int i = local * blockDim.x + threadIdx.x;
    int stride = NB_H * blockDim.x;
    int tot = E1 + E2 + E3;
    for (; i < tot; i += stride) {
      if (i < E1) atomicAdd(&c1[d1[i]], 1);
      else if (i < E1 + E2) atomicAdd(&c2[d2[i - E1]], 1);
      else atomicAdd(&c3[d3[i - E1 - E2]], 1);
    }
  }
}

// ------------- CSR scans + bucket -------------
__global__ void scan512_3(const int* __restrict__ c1, int* __restrict__ o1, int ns1,
                          const int* __restrict__ c2, int* __restrict__ o2, int ns2,
                          const int* __restrict__ c3, int* __restrict__ o3, int ns3,
                          int* __restrict__ bsum) {
  const int* in; int* out; int ns;
  switch (blockIdx.y) {
    case 0: in = c1; out = o1; ns = ns1; break;
    case 1: in = c2; out = o2; ns = ns2; break;
    default: in = c3; out = o3; ns = ns3; break;
  }
  if ((int)blockIdx.x * 512 >= ns) return;
  __shared__ int s[512];
  int t = threadIdx.x;
  int i = blockIdx.x * 512 + t;
  int v = (i < ns) ? in[i] : 0;
  s[t] = v;
  __syncthreads();
  for (int off = 1; off < 512; off <<= 1) {
    int x = s[t];
    int y = (t >= off) ? s[t - off] : 0;
    __syncthreads();
    s[t] = x + y;
    __syncthreads();
  }
  if (i < ns) out[i] = s[t] - v;  // exclusive
  if (t == 511) bsum[blockIdx.y * 512 + blockIdx.x] = s[511];
}

__global__ void scan_bsums3(int* __restrict__ bsum, int B1, int B2, int B3) {
  int rel = blockIdx.x;
  int B = rel == 0 ? B1 : (rel == 1 ? B2 : B3);
  int* bs = bsum + rel * 512;
  __shared__ int s[512];
  int t = threadIdx.x;
  int v = (t < B) ? bs[t] : 0;
  s[t] = v;
  __syncthreads();
  for (int off = 1; off < 512; off <<= 1) {
    int x = s[t];
    int y = (t >= off) ? s[t - off] : 0;
    __syncthreads();
    s[t] = x + y;
    __syncthreads();
  }
  if (t < B) bs[t] = s[t] - v;  // exclusive
}

// add block offsets; seed pos[]; also emit float counts for rel2/rel3
__global__ void addoff3(int* __restrict__ o1, int* __restrict__ p1, int ns1,
                        int* __restrict__ o2, int* __restrict__ p2, int ns2,
                        int* __restrict__ o3, int* __restrict__ p3, int ns3,
                        const int* __restrict__ bsum,
                        const int* __restrict__ c2, float* __restrict__ f2,
                        const int* __restrict__ c3, float* __restrict__ f3) {
  int* o; int* p; int ns;
  switch (blockIdx.y) {
    case 0: o = o1; p = p1; ns = ns1; break;
    case 1: o = o2; p = p2; ns = ns2; break;
    default: o = o3; p = p3; ns = ns3; break;
  }
  int i = blockIdx.x * 512 + threadIdx.x;
  if (i < ns) {
    int v = o[i] + bsum[blockIdx.y * 512 + blockIdx.x];
    o[i] = v;
    p[i] = v;
    if (blockIdx.y == 1) f2[i] = (float)c2[i];
    else if (blockIdx.y == 2) f3[i] = (float)c3[i];
  }
}

__global__ void bucket3(
    const int* __restrict__ d1, const int* __restrict__ s1in,
    const float* __restrict__ w1in, int E1, int* __restrict__ p1,
    int* __restrict__ s1, float* __restrict__ w1,
    const int* __restrict__ d2, const int* __restrict__ s2in, int E2,
    int* __restrict__ p2, int* __restrict__ s2,
    const int* __restrict__ d3, const int* __restrict__ s3in, int E3,
    int* __restrict__ p3, int* __restrict__ s3) {
  int i = blockIdx.x * blockDim.x + threadIdx.x;
  int stride = gridDim.x * blockDim.x;
  int tot = E1 + E2 + E3;
  for (; i < tot; i += stride) {
    if (i < E1) {
      int p = atomicAdd(&p1[d1[i]], 1);
      s1[p] = s1in[i];
      w1[p] = w1in[i];
    } else if (i < E1 + E2) {
      int k = i - E1;
      int p = atomicAdd(&p2[d2[k]], 1);
      s2[p] = s2in[k];
    } else {
      int k = i - E1 - E2;
      int p = atomicAdd(&p3[d3[k]], 1);
      s3[p] = s3in[k];
    }
  }
}

// ------------- feature aggregation (1 wave per dst row, combined-stream 4-wide) -------------
__global__ void aggregate3(
    const unsigned short* __restrict__ Axp, const unsigned short* __restrict__ Axa,
    int Np, int Na,
    const int* __restrict__ off1, const int* __restrict__ s1,
    const float* __restrict__ w1,
    const int* __restrict__ off2, const int* __restrict__ s2,
    const int* __restrict__ off3, const int* __restrict__ s3,
    unsigned short* __restrict__ agg_c, unsigned short* __restrict__ agg_w,
    unsigned short* __restrict__ agg_wr, float* __restrict__ wdeg) {
  int gw = (blockIdx.x * blockDim.x + threadIdx.x) >> 6;
  int lane = threadIdx.x & 63;
  if (gw < Np) {
    float4 vc = {0.f, 0.f, 0.f, 0.f};
    float4 vw = {0.f, 0.f, 0.f, 0.f};
    float wd = 0.f;
    const int j1 = off1[gw], e1 = off1[gw + 1];
    const int j2 = off2[gw], e2 = off2[gw + 1];
    const int n1 = e1 - j1;
    const int T = n1 + (e2 - j2);
    int t = 0;
    // combined stream: slot source is a pure (wave-uniform) function of position
    for (; t + 4 <= T; t += 4) {
      ushort4 mm[4];
      float wc_s[4], ww_s[4];
#pragma unroll
      for (int u = 0; u < 4; ++u) {
        int p = t + u;
        bool c = p < n1;
        int idx = c ? j1 + p : j2 + (p - n1);
        const int* sp = c ? s1 : s2;
        int src = sp[idx];
        const unsigned short* bp = c ? Axp : Axa;
        mm[u] = *(const ushort4*)(bp + ((size_t)src << 8) + lane * 4);
        float w = 1.f;
        if (c) w = w1[idx];
        wc_s[u] = c ? w : 0.f;   // cites blend weight
        ww_s[u] = c ? 0.f : 1.f; // writes blend weight
      }
#pragma unroll
      for (int u = 0; u < 4; ++u) {
        float fx = b2f(mm[u].x), fy = b2f(mm[u].y);
        float fz = b2f(mm[u].z), fw = b2f(mm[u].w);
        vc.x += wc_s[u] * fx; vc.y += wc_s[u] * fy;
        vc.z += wc_s[u] * fz; vc.w += wc_s[u] * fw;
        vw.x += ww_s[u] * fx; vw.y += ww_s[u] * fy;
        vw.z += ww_s[u] * fz; vw.w += ww_s[u] * fw;
        wd += wc_s[u];
      }
    }
    for (; t < T; ++t) {
      bool c = t < n1;
      int idx = c ? j1 + t : j2 + (t - n1);
      const int* sp = c ? s1 : s2;
      int src = sp[idx];
      const unsigned short* bp = c ? Axp : Axa;
      ushort4 m = *(const ushort4*)(bp + ((size_t)src << 8) + lane * 4);
      float w = 1.f;
      if (c) w = w1[idx];
      float wc_b = c ? w : 0.f, ww_b = c ? 0.f : 1.f;
      float fx = b2f(m.x), fy = b2f(m.y), fz = b2f(m.z), fw = b2f(m.w);
      vc.x += wc_b * fx; vc.y += wc_b * fy; vc.z += wc_b * fz; vc.w += wc_b * fw;
      vw.x += ww_b * fx; vw.y += ww_b * fy; vw.z += ww_b * fz; vw.w += ww_b * fw;
      wd += wc_b;
    }
    ushort4 oc, ow;
    oc.x = f2b(vc.x); oc.y = f2b(vc.y); oc.z = f2b(vc.z); oc.w = f2b(vc.w);
    ow.x = f2b(vw.x); ow.y = f2b(vw.y); ow.z = f2b(vw.z); ow.w = f2b(vw.w);
    *(ushort4*)(agg_c + ((size_t)gw << 8) + lane * 4) = oc;
    *(ushort4*)(agg_w + ((size_t)gw << 8) + lane * 4) = ow;
    if (lane == 0) wdeg[gw] = wd;
  } else if (gw < Np + Na) {
    int r = gw - Np;
    float4 v = {0.f, 0.f, 0.f, 0.f};
    int j = off3[r], e = off3[r + 1];
    for (; j + 4 <= e; j += 4) {
      int sa = s3[j], sb = s3[j + 1], sc = s3[j + 2], sd = s3[j + 3];
      ushort4 ma = *(const ushort4*)(Axp + ((size_t)sa << 8) + lane * 4);
      ushort4 mb = *(const ushort4*)(Axp + ((size_t)sb << 8) + lane * 4);
      ushort4 mc = *(const ushort4*)(Axp + ((size_t)sc << 8) + lane * 4);
      ushort4 md = *(const ushort4*)(Axp + ((size_t)sd << 8) + lane * 4);
      v.x += b2f(ma.x) + b2f(mb.x) + b2f(mc.x) + b2f(md.x);
      v.y += b2f(ma.y) + b2f(mb.y) + b2f(mc.y) + b2f(md.y);
      v.z += b2f(ma.z) + b2f(mb.z) + b2f(mc.z) + b2f(md.z);
      v.w += b2f(ma.w) + b2f(mb.w) + b2f(mc.w) + b2f(md.w);
    }
    if (j + 2 <= e) {
      int sa = s3[j], sb = s3[j + 1];
      ushort4 ma = *(const ushort4*)(Axp + ((size_t)sa << 8) + lane * 4);
      ushort4 mb = *(const ushort4*)(Axp + ((size_t)sb << 8) + lane * 4);
      v.x += b2f(ma.x) + b2f(mb.x); v.y += b2f(ma.y) + b2f(mb.y);
      v.z += b2f(ma.z) + b2f(mb.z); v.w += b2f(ma.w) + b2f(mb.w);
      j += 2;
    }
    if (j < e) {
      int sa = s3[j];
      ushort4 ma = *(const ushort4*)(Axp + ((size_t)sa << 8) + lane * 4);
      v.x += b2f(ma.x); v.y += b2f(ma.y); v.z += b2f(ma.z); v.w += b2f(ma.w);
    }
    ushort4 o;
    o.x = f2b(v.x); o.y = f2b(v.y); o.z = f2b(v.z); o.w = f2b(v.w);
    *(ushort4*)(agg_wr + ((size_t)r << 8) + lane * 4) = o;
  }
}

// ------------- final GEMM: out = [A0|A1|A2] @ [B0;B1;B2] + row/col bias, ELU -------------
// 128x128 tile, BK=64, 4 waves (2x2), wave tile 64x64. All-bf16 A operands.
template <int NKT>
__device__ __forceinline__ void gemm_final_body(
    uint8_t* lds,
    const unsigned short* __restrict__ A0, const unsigned short* __restrict__ A1,
    const unsigned short* __restrict__ A2,
    const unsigned short* __restrict__ B0, const unsigned short* __restrict__ B1,
    const unsigned short* __restrict__ B2,
    const float* __restrict__ bias0, const float* __restrict__ bias1,
    const float* __restrict__ bias2,
    const float* __restrict__ rs1, const float* __restrict__ rs2,
    float* __restrict__ outp, int M, int row0, int n0, int tid) {
  uint8_t* ldsA = lds;            // 16 KB
  uint8_t* ldsB = lds + 16384;    // 16 KB
  const int lane = tid & 63;
  const int w = tid >> 6;
  const int wr = w >> 1, wc = w & 1;

  f32x4 acc[4][4] = {};

  for (int kt = 0; kt < NKT; ++kt) {
    const int kk = (kt & 3) << 6;
    const int sel = kt >> 2;
    const unsigned short* B = sel == 0 ? B0 : (sel == 1 ? B1 : B2);
    const unsigned short* A = sel == 0 ? A0 : (sel == 1 ? A1 : A2);
#pragma unroll
    for (int c = 0; c < 4; ++c) {
      int qq = c * 256 + tid;
      int row = qq >> 3, ch = qq & 7;
      int lch = ch ^ (row & 7);
      load_lds16(B + (size_t)(n0 + row) * 256 + kk + lch * 8, ldsB + qq * 16);
    }
#pragma unroll
    for (int c = 0; c < 4; ++c) {
      int qq = c * 256 + tid;
      int row = qq >> 3, ch = qq & 7;
      int lch = ch ^ (row & 7);
      int ar = row0 + row;
      if (ar >= M) ar = M - 1;
      load_lds16(A + (size_t)ar * 256 + kk + lch * 8, ldsA + qq * 16);
    }
    asm volatile("s_waitcnt vmcnt(0)" ::: "memory");
    __syncthreads();

#pragma unroll
    for (int s = 0; s < 2; ++s) {
      const int cbase = (s << 2) + (lane >> 4);
      short8 av[4];
#pragma unroll
      for (int m = 0; m < 4; ++m) {
        int rrow = wr * 64 + m * 16 + (lane & 15);
        av[m] = *(const short8*)(ldsA + rrow * 128 + ((cbase ^ (rrow & 7)) << 4));
      }
      short8 bv[4];
#pragma unroll
      for (int n = 0; n < 4; ++n) {
        int cc = wc * 64 + n * 16 + (lane & 15);
        bv[n] = *(const short8*)(ldsB + cc * 128 + ((cbase ^ (cc & 7)) << 4));
      }
#pragma unroll
      for (int m = 0; m < 4; ++m)
#pragma unroll
        for (int n = 0; n < 4; ++n)
          acc[m][n] = __builtin_amdgcn_mfma_f32_16x16x32_bf16(av[m], bv[n],
                                                              acc[m][n], 0, 0, 0);
    }
    __syncthreads();
  }

  // epilogue: combined bias + ELU, single f32 store
  float c0[4], c1v[4], c2v[4];
#pragma unroll
  for (int n = 0; n < 4; ++n) {
    int col = n0 + wc * 64 + n * 16 + (lane & 15);
    c0[n] = bias0[col];
    c1v[n] = bias1[col];
    c2v[n] = bias2 ? bias2[col] : 0.f;
  }
#pragma unroll
  for (int m = 0; m < 4; ++m) {
#pragma unroll
    for (int j = 0; j < 4; ++j) {
      int row = row0 + wr * 64 + m * 16 + (lane >> 4) * 4 + j;
      if (row < M) {
        float r1 = rs1[row];
        float r2 = rs2 ? rs2[row] : 0.f;
#pragma unroll
        for (int n = 0; n < 4; ++n) {
          int col = n0 + wc * 64 + n * 16 + (lane & 15);
          float v = acc[m][n][j] + c0[n] + r1 * c1v[n] + r2 * c2v[n];
          outp[(size_t)row * 256 + col] = elu1(v);
        }
      }
    }
  }
}

__global__ __launch_bounds__(256, 3) void gemm_final(
    const unsigned short* __restrict__ Axp, const unsigned short* __restrict__ Axa,
    const unsigned short* __restrict__ agg_c, const unsigned short* __restrict__ agg_w,
    const unsigned short* __restrict__ agg_wr,
    const unsigned short* __restrict__ WT_sp, const unsigned short* __restrict__ WT_c,
    const unsigned short* __restrict__ WT_w, const unsigned short* __restrict__ WT_sa,
    const unsigned short* __restrict__ WT_wr,
    const float* __restrict__ b_sp, const float* __restrict__ b_c,
    const float* __restrict__ b_w, const float* __restrict__ b_sa,
    const float* __restrict__ b_wr,
    const float* __restrict__ wdeg, const float* __restrict__ cntw_f,
    const float* __restrict__ cntwr_f,
    float* __restrict__ out_p, float* __restrict__ out_a,
    int Mp, int Ma, int nwgp, int nwg) {
  __shared__ uint8_t lds[32768];
  // bijective XCD swizzle (m204)
  const int orig = blockIdx.x;
  const int q = nwg >> 3, r = nwg & 7;
  const int xcd = orig & 7, idx = orig >> 3;
  const int wgid = (xcd < r ? xcd * (q + 1) : r * (q + 1) + (xcd - r) * q) + idx;
  const int tid = threadIdx.x;
  if (wgid < nwgp) {
    gemm_final_body<12>(lds, Axp, agg_c, agg_w,
                        WT_sp, WT_c, WT_w,
                        b_sp, b_c, b_w, wdeg, cntw_f,
                        out_p, Mp, (wgid >> 1) * 128, (wgid & 1) * 128, tid);
  } else {
    int w2 = wgid - nwgp;
    gemm_final_body<8>(lds, Axa, agg_wr, nullptr,
                       WT_sa, WT_wr, nullptr,
                       b_sa, b_wr, nullptr, cntwr_f, nullptr,
                       out_a, Ma, (w2 >> 1) * 128, (w2 & 1) * 128, tid);
  }
}

extern "C" void kernel_launch(void* const* d_in, const int* in_sizes, int n_in,
                              void* d_out, int out_size, void* d_ws, size_t ws_size,
                              hipStream_t stream) {
  const float* x_p = (const float*)d_in[0];
  const float* x_a = (const float*)d_in[1];
  const int* c_src = (const int*)d_in[2];
  const int* c_dst = (const int*)d_in[3];
  const float* c_w = (const float*)d_in[4];
  const int* w_src = (const int*)d_in[5];
  const int* w_dst = (const int*)d_in[6];
  const int* wr_src = (const int*)d_in[7];
  const int* wr_dst = (const int*)d_in[8];
  const float* W_sp = (const float*)d_in[9];
  const float* b_sp = (const float*)d_in[10];
  const float* W_sa = (const float*)d_in[11];
  const float* b_sa = (const float*)d_in[12];
  const float* W_c  = (const float*)d_in[13];
  const float* b_c  = (const float*)d_in[14];
  const float* W_w  = (const float*)d_in[15];
  const float* b_w  = (const float*)d_in[16];
  const float* W_wr = (const float*)d_in[17];
  const float* b_wr = (const float*)d_in[18];

  const int Mp = in_sizes[0] / 256;
  const int Ma = in_sizes[1] / 256;
  const int Ec = in_sizes[2], Ew = in_sizes[5], Ewr = in_sizes[7];

  // ---- workspace bump allocator (256B aligned); total ~216 MB ----
  size_t wo = 0;
  auto alloc = [&](size_t bytes) -> void* {
    void* p = (char*)d_ws + wo;
    wo += (bytes + 255) & ~(size_t)255;
    return p;
  };
  unsigned short* Axp    = (unsigned short*)alloc((size_t)Mp * 512);  // bf16 x_p
  unsigned short* Axa    = (unsigned short*)alloc((size_t)Ma * 512);  // bf16 x_a
  unsigned short* agg_c  = (unsigned short*)alloc((size_t)Mp * 512);
  unsigned short* agg_w  = (unsigned short*)alloc((size_t)Mp * 512);
  unsigned short* agg_wr = (unsigned short*)alloc((size_t)Ma * 512);
  unsigned short* WT_sp = (unsigned short*)alloc(131072);
  unsigned short* WT_sa = (unsigned short*)alloc(131072);
  unsigned short* WT_c  = (unsigned short*)alloc(131072);
  unsigned short* WT_w  = (unsigned short*)alloc(131072);
  unsigned short* WT_wr = (unsigned short*)alloc(131072);
  int* cnt_c  = (int*)alloc((size_t)((Mp + 1) + (Mp + 1) + (Ma + 1)) * 4);
  int* cnt_w  = cnt_c + (Mp + 1);
  int* cnt_wr = cnt_w + (Mp + 1);
  size_t cnt_bytes = (size_t)((Mp + 1) + (Mp + 1) + (Ma + 1)) * 4;
  int* off_c  = (int*)alloc((size_t)(Mp + 1) * 4);
  int* pos_c  = (int*)alloc((size_t)(Mp + 1) * 4);
  int* off_w  = (int*)alloc((size_t)(Mp + 1) * 4);
  int* pos_w  = (int*)alloc((size_t)(Mp + 1) * 4);
  int* off_wr = (int*)alloc((size_t)(Ma + 1) * 4);
  int* pos_wr = (int*)alloc((size_t)(Ma + 1) * 4);
  int* srcs_c  = (int*)alloc((size_t)Ec * 4);
  float* wgts_c = (float*)alloc((size_t)Ec * 4);
  int* srcs_w  = (int*)alloc((size_t)Ew * 4);
  int* srcs_wr = (int*)alloc((size_t)Ewr * 4);
  int* bsum = (int*)alloc(3 * 512 * 4);
  float* wdeg = (float*)alloc((size_t)Mp * 4);
  float* cntw_f = (float*)alloc((size_t)(Mp + 1) * 4);
  float* cntwr_f = (float*)alloc((size_t)(Ma + 1) * 4);

  float* out_p = (float*)d_out;
  float* out_a = (float*)d_out + (size_t)Mp * 256;

  // ---- prep (1 dispatch): cvt (x_p + x_a) || transposes || hist ----
  hipMemsetAsync(cnt_c, 0, cnt_bytes, stream);
  prep_all<<<NB_CVT + NB_T + NB_H, 256, 0, stream>>>(
      (const float4*)x_p, (ushort4*)Axp, Mp * 64,
      (const float4*)x_a, (ushort4*)Axa, Ma * 64,
      W_sp, W_sa, W_c, W_w, W_wr,
      WT_sp, WT_sa, WT_c, WT_w, WT_wr,
      c_dst, Ec, cnt_c, w_dst, Ew, cnt_w, wr_dst, Ewr, cnt_wr);

  // ---- CSR scans + bucket (cnt->float folded into addoff3) ----
  const int ns1 = Mp + 1, ns2 = Mp + 1, ns3 = Ma + 1;
  const int B1 = (ns1 + 511) / 512, B2 = (ns2 + 511) / 512, B3 = (ns3 + 511) / 512;
  const int Bmax = B1 > B2 ? (B1 > B3 ? B1 : B3) : (B2 > B3 ? B2 : B3);
  {
    dim3 g(Bmax, 3);
    scan512_3<<<g, 512, 0, stream>>>(cnt_c, off_c, ns1, cnt_w, off_w, ns2,
                                     cnt_wr, off_wr, ns3, bsum);
    scan_bsums3<<<3, 512, 0, stream>>>(bsum, B1, B2, B3);
    addoff3<<<g, 512, 0, stream>>>(off_c, pos_c, ns1, off_w, pos_w, ns2,
                                   off_wr, pos_wr, ns3, bsum,
                                   cnt_w, cntw_f, cnt_wr, cntwr_f);
  }
  bucket3<<<256, 256, 0, stream>>>(c_dst, c_src, c_w, Ec, pos_c, srcs_c, wgts_c,
                                   w_dst, w_src, Ew, pos_w, srcs_w,
                                   wr_dst, wr_src, Ewr, pos_wr, srcs_wr);

  // ---- feature aggregation (combined-stream 4-wide) ----
  {
    int totalWaves = Mp + Ma;
    aggregate3<<<(totalWaves + 3) / 4, 256, 0, stream>>>(
        Axp, Axa, Mp, Ma,
        off_c, srcs_c, wgts_c, off_w, srcs_w, off_wr, srcs_wr,
        agg_c, agg_w, agg_wr, wdeg);
  }

  // ---- final fused GEMM (K=768 paper / K=512 author) + bias + ELU ----
  {
    const int nsp = (Mp + 127) / 128, nsa = (Ma + 127) / 128;
    const int nwgp = nsp * 2, nwga = nsa * 2;
    gemm_final<<<nwgp + nwga, 256, 0, stream>>>(
        Axp, Axa, agg_c, agg_w, agg_wr,
        WT_sp, WT_c, WT_w, WT_sa, WT_wr,
        b_sp, b_c, b_w, b_sa, b_wr,
        wdeg, cntw_f, cntwr_f,
        out_p, out_a, Mp, Ma, nwgp, nwgp + nwga);
  }
}

// Round 24
// 312.014 us; speedup vs baseline: 1.0250x; 1.0250x over previous
//
#include <hip/hip_runtime.h>
#include <stdint.h>

typedef __attribute__((ext_vector_type(8))) short short8;
typedef __attribute__((ext_vector_type(4))) float f32x4;

__device__ __forceinline__ unsigned short f2b(float f) {
  union { float f; uint32_t u; } v; v.f = f;
  uint32_t r = (v.u + 0x7fffu + ((v.u >> 16) & 1u)) >> 16;
  return (unsigned short)r;
}
__device__ __forceinline__ float b2f(unsigned short h) {
  union { uint32_t u; float f; } v; v.u = ((uint32_t)h) << 16; return v.f;
}

__device__ __forceinline__ void load_lds16(const void* g, void* l) {
  __builtin_amdgcn_global_load_lds(
      (const __attribute__((address_space(1))) uint32_t*)g,
      (__attribute__((address_space(3))) uint32_t*)l, 16, 0, 0);
}

__device__ __forceinline__ float elu1(float v) {
  return v > 0.f ? v : expf(v) - 1.f;
}

// ------------- merged prep: cvt (x_p,x_a->bf16) || 5x transpose+cast || hist3 -------------
#define NB_CVT 1024
#define NB_T 320
#define NB_H 256
__global__ void prep_all(
    const float4* __restrict__ xp_in, ushort4* __restrict__ xp_out, int n4p,
    const float4* __restrict__ xa_in, ushort4* __restrict__ xa_out, int n4a,
    const float* __restrict__ W0, const float* __restrict__ W1,
    const float* __restrict__ W2, const float* __restrict__ W3,
    const float* __restrict__ W4,
    unsigned short* __restrict__ T0, unsigned short* __restrict__ T1,
    unsigned short* __restrict__ T2, unsigned short* __restrict__ T3,
    unsigned short* __restrict__ T4,
    const int* __restrict__ d1, int E1, int* __restrict__ c1,
    const int* __restrict__ d2, int E2, int* __restrict__ c2,
    const int* __restrict__ d3, int E3, int* __restrict__ c3) {
  __shared__ unsigned short t[32][33];
  const int bid = blockIdx.x;
  if (bid < NB_CVT) {
    int i = bid * blockDim.x + threadIdx.x;
    int stride = NB_CVT * blockDim.x;
    int tot = n4p + n4a;
    for (; i < tot; i += stride) {
      const float4 f = (i < n4p) ? xp_in[i] : xa_in[i - n4p];
      ushort4 o;
      o.x = f2b(f.x); o.y = f2b(f.y); o.z = f2b(f.z); o.w = f2b(f.w);
      if (i < n4p) xp_out[i] = o;
      else xa_out[i - n4p] = o;
    }
  } else if (bid < NB_CVT + NB_T) {
    int local = bid - NB_CVT;
    int mat = local >> 6, bt = local & 63;
    const float* W; unsigned short* T;
    switch (mat) {
      case 0: W = W0; T = T0; break;
      case 1: W = W1; T = T1; break;
      case 2: W = W2; T = T2; break;
      case 3: W = W3; T = T3; break;
      default: W = W4; T = T4; break;
    }
    int bx = bt & 7, by = bt >> 3;
    int x = threadIdx.x & 31, y = threadIdx.x >> 5;  // 32x8
    for (int i = 0; i < 32; i += 8)
      t[y + i][x] = f2b(W[(by * 32 + y + i) * 256 + bx * 32 + x]);
    __syncthreads();
    for (int i = 0; i < 32; i += 8)
      T[(bx * 32 + y + i) * 256 + by * 32 + x] = t[x][y + i];
  } else {
    int local = bid - NB_CVT - NB_T;
    int i = local * blockDim.x + threadIdx.x;
    int stride = NB_H * blockDim.x;
    int tot = E1 + E2 + E3;
    for (; i < tot; i += stride) {
      if (i < E1) atomicAdd(&c1[d1[i]], 1);
      else if (i < E1 + E2) atomicAdd(&c2[d2[i - E1]], 1);
      else atomicAdd(&c3[d3[i - E1 - E2]], 1);
    }
  }
}

// ------------- CSR scans + bucket -------------
__global__ void scan512_3(const int* __restrict__ c1, int* __restrict__ o1, int ns1,
                          const int* __restrict__ c2, int* __restrict__ o2, int ns2,
                          const int* __restrict__ c3, int* __restrict__ o3, int ns3,
                          int* __restrict__ bsum) {
  const int* in; int* out; int ns;
  switch (blockIdx.y) {
    case 0: in = c1; out = o1; ns = ns1; break;
    case 1: in = c2; out = o2; ns = ns2; break;
    default: in = c3; out = o3; ns = ns3; break;
  }
  if ((int)blockIdx.x * 512 >= ns) return;
  __shared__ int s[512];
  int t = threadIdx.x;
  int i = blockIdx.x * 512 + t;
  int v = (i < ns) ? in[i] : 0;
  s[t] = v;
  __syncthreads();
  for (int off = 1; off < 512; off <<= 1) {
    int x = s[t];
    int y = (t >= off) ? s[t - off] : 0;
    __syncthreads();
    s[t] = x + y;
    __syncthreads();
  }
  if (i < ns) out[i] = s[t] - v;  // exclusive
  if (t == 511) bsum[blockIdx.y * 512 + blockIdx.x] = s[511];
}

__global__ void scan_bsums3(int* __restrict__ bsum, int B1, int B2, int B3) {
  int rel = blockIdx.x;
  int B = rel == 0 ? B1 : (rel == 1 ? B2 : B3);
  int* bs = bsum + rel * 512;
  __shared__ int s[512];
  int t = threadIdx.x;
  int v = (t < B) ? bs[t] : 0;
  s[t] = v;
  __syncthreads();
  for (int off = 1; off < 512; off <<= 1) {
    int x = s[t];
    int y = (t >= off) ? s[t - off] : 0;
    __syncthreads();
    s[t] = x + y;
    __syncthreads();
  }
  if (t < B) bs[t] = s[t] - v;  // exclusive
}

// add block offsets; seed pos[]; also emit float counts for rel2/rel3
__global__ void addoff3(int* __restrict__ o1, int* __restrict__ p1, int ns1,
                        int* __restrict__ o2, int* __restrict__ p2, int ns2,
                        int* __restrict__ o3, int* __restrict__ p3, int ns3,
                        const int* __restrict__ bsum,
                        const int* __restrict__ c2, float* __restrict__ f2,
                        const int* __restrict__ c3, float* __restrict__ f3) {
  int* o; int* p; int ns;
  switch (blockIdx.y) {
    case 0: o = o1; p = p1; ns = ns1; break;
    case 1: o = o2; p = p2; ns = ns2; break;
    default: o = o3; p = p3; ns = ns3; break;
  }
  int i = blockIdx.x * 512 + threadIdx.x;
  if (i < ns) {
    int v = o[i] + bsum[blockIdx.y * 512 + blockIdx.x];
    o[i] = v;
    p[i] = v;
    if (blockIdx.y == 1) f2[i] = (float)c2[i];
    else if (blockIdx.y == 2) f3[i] = (float)c3[i];
  }
}

__global__ void bucket3(
    const int* __restrict__ d1, const int* __restrict__ s1in,
    const float* __restrict__ w1in, int E1, int* __restrict__ p1,
    int* __restrict__ s1, float* __restrict__ w1,
    const int* __restrict__ d2, const int* __restrict__ s2in, int E2,
    int* __restrict__ p2, int* __restrict__ s2,
    const int* __restrict__ d3, const int* __restrict__ s3in, int E3,
    int* __restrict__ p3, int* __restrict__ s3) {
  int i = blockIdx.x * blockDim.x + threadIdx.x;
  int stride = gridDim.x * blockDim.x;
  int tot = E1 + E2 + E3;
  for (; i < tot; i += stride) {
    if (i < E1) {
      int p = atomicAdd(&p1[d1[i]], 1);
      s1[p] = s1in[i];
      w1[p] = w1in[i];
    } else if (i < E1 + E2) {
      int k = i - E1;
      int p = atomicAdd(&p2[d2[k]], 1);
      s2[p] = s2in[k];
    } else {
      int k = i - E1 - E2;
      int p = atomicAdd(&p3[d3[k]], 1);
      s3[p] = s3in[k];
    }
  }
}

// ------------- feature aggregation: relation-split waves -------------
// wave gw < Np        : cites list of paper row gw  -> agg_c, wdeg (weighted)
// Np <= gw < 2Np      : writes list of paper row gw-Np -> agg_w
// 2Np <= gw < 2Np+Na  : written list of author row  -> agg_wr
__global__ void aggregate3(
    const unsigned short* __restrict__ Axp, const unsigned short* __restrict__ Axa,
    int Np, int Na,
    const int* __restrict__ off1, const int* __restrict__ s1,
    const float* __restrict__ w1,
    const int* __restrict__ off2, const int* __restrict__ s2,
    const int* __restrict__ off3, const int* __restrict__ s3,
    unsigned short* __restrict__ agg_c, unsigned short* __restrict__ agg_w,
    unsigned short* __restrict__ agg_wr, float* __restrict__ wdeg) {
  int gw = (blockIdx.x * blockDim.x + threadIdx.x) >> 6;
  int lane = threadIdx.x & 63;
  if (gw < Np) {
    // cites: weighted 4-wide
    float4 v = {0.f, 0.f, 0.f, 0.f};
    float wd = 0.f;
    int j = off1[gw], e = off1[gw + 1];
    for (; j + 4 <= e; j += 4) {
      int sa = s1[j], sb = s1[j + 1], sc = s1[j + 2], sd = s1[j + 3];
      float wa = w1[j], wb = w1[j + 1], wc = w1[j + 2], wdd = w1[j + 3];
      ushort4 ma = *(const ushort4*)(Axp + ((size_t)sa << 8) + lane * 4);
      ushort4 mb = *(const ushort4*)(Axp + ((size_t)sb << 8) + lane * 4);
      ushort4 mc = *(const ushort4*)(Axp + ((size_t)sc << 8) + lane * 4);
      ushort4 md = *(const ushort4*)(Axp + ((size_t)sd << 8) + lane * 4);
      v.x += wa * b2f(ma.x) + wb * b2f(mb.x) + wc * b2f(mc.x) + wdd * b2f(md.x);
      v.y += wa * b2f(ma.y) + wb * b2f(mb.y) + wc * b2f(mc.y) + wdd * b2f(md.y);
      v.z += wa * b2f(ma.z) + wb * b2f(mb.z) + wc * b2f(mc.z) + wdd * b2f(md.z);
      v.w += wa * b2f(ma.w) + wb * b2f(mb.w) + wc * b2f(mc.w) + wdd * b2f(md.w);
      wd += wa + wb + wc + wdd;
    }
    if (j + 2 <= e) {
      int sa = s1[j], sb = s1[j + 1];
      float wa = w1[j], wb = w1[j + 1];
      ushort4 ma = *(const ushort4*)(Axp + ((size_t)sa << 8) + lane * 4);
      ushort4 mb = *(const ushort4*)(Axp + ((size_t)sb << 8) + lane * 4);
      v.x += wa * b2f(ma.x) + wb * b2f(mb.x);
      v.y += wa * b2f(ma.y) + wb * b2f(mb.y);
      v.z += wa * b2f(ma.z) + wb * b2f(mb.z);
      v.w += wa * b2f(ma.w) + wb * b2f(mb.w);
      wd += wa + wb;
      j += 2;
    }
    if (j < e) {
      int sa = s1[j];
      float wa = w1[j];
      ushort4 ma = *(const ushort4*)(Axp + ((size_t)sa << 8) + lane * 4);
      v.x += wa * b2f(ma.x); v.y += wa * b2f(ma.y);
      v.z += wa * b2f(ma.z); v.w += wa * b2f(ma.w);
      wd += wa;
    }
    ushort4 o;
    o.x = f2b(v.x); o.y = f2b(v.y); o.z = f2b(v.z); o.w = f2b(v.w);
    *(ushort4*)(agg_c + ((size_t)gw << 8) + lane * 4) = o;
    if (lane == 0) wdeg[gw] = wd;
  } else if (gw < 2 * Np) {
    // writes: unweighted 4-wide
    int r = gw - Np;
    float4 v = {0.f, 0.f, 0.f, 0.f};
    int j = off2[r], e = off2[r + 1];
    for (; j + 4 <= e; j += 4) {
      int sa = s2[j], sb = s2[j + 1], sc = s2[j + 2], sd = s2[j + 3];
      ushort4 ma = *(const ushort4*)(Axa + ((size_t)sa << 8) + lane * 4);
      ushort4 mb = *(const ushort4*)(Axa + ((size_t)sb << 8) + lane * 4);
      ushort4 mc = *(const ushort4*)(Axa + ((size_t)sc << 8) + lane * 4);
      ushort4 md = *(const ushort4*)(Axa + ((size_t)sd << 8) + lane * 4);
      v.x += b2f(ma.x) + b2f(mb.x) + b2f(mc.x) + b2f(md.x);
      v.y += b2f(ma.y) + b2f(mb.y) + b2f(mc.y) + b2f(md.y);
      v.z += b2f(ma.z) + b2f(mb.z) + b2f(mc.z) + b2f(md.z);
      v.w += b2f(ma.w) + b2f(mb.w) + b2f(mc.w) + b2f(md.w);
    }
    if (j + 2 <= e) {
      int sa = s2[j], sb = s2[j + 1];
      ushort4 ma = *(const ushort4*)(Axa + ((size_t)sa << 8) + lane * 4);
      ushort4 mb = *(const ushort4*)(Axa + ((size_t)sb << 8) + lane * 4);
      v.x += b2f(ma.x) + b2f(mb.x); v.y += b2f(ma.y) + b2f(mb.y);
      v.z += b2f(ma.z) + b2f(mb.z); v.w += b2f(ma.w) + b2f(mb.w);
      j += 2;
    }
    if (j < e) {
      int sa = s2[j];
      ushort4 ma = *(const ushort4*)(Axa + ((size_t)sa << 8) + lane * 4);
      v.x += b2f(ma.x); v.y += b2f(ma.y); v.z += b2f(ma.z); v.w += b2f(ma.w);
    }
    ushort4 o;
    o.x = f2b(v.x); o.y = f2b(v.y); o.z = f2b(v.z); o.w = f2b(v.w);
    *(ushort4*)(agg_w + ((size_t)r << 8) + lane * 4) = o;
  } else if (gw < 2 * Np + Na) {
    int r = gw - 2 * Np;
    float4 v = {0.f, 0.f, 0.f, 0.f};
    int j = off3[r], e = off3[r + 1];
    for (; j + 4 <= e; j += 4) {
      int sa = s3[j], sb = s3[j + 1], sc = s3[j + 2], sd = s3[j + 3];
      ushort4 ma = *(const ushort4*)(Axp + ((size_t)sa << 8) + lane * 4);
      ushort4 mb = *(const ushort4*)(Axp + ((size_t)sb << 8) + lane * 4);
      ushort4 mc = *(const ushort4*)(Axp + ((size_t)sc << 8) + lane * 4);
      ushort4 md = *(const ushort4*)(Axp + ((size_t)sd << 8) + lane * 4);
      v.x += b2f(ma.x) + b2f(mb.x) + b2f(mc.x) + b2f(md.x);
      v.y += b2f(ma.y) + b2f(mb.y) + b2f(mc.y) + b2f(md.y);
      v.z += b2f(ma.z) + b2f(mb.z) + b2f(mc.z) + b2f(md.z);
      v.w += b2f(ma.w) + b2f(mb.w) + b2f(mc.w) + b2f(md.w);
    }
    if (j + 2 <= e) {
      int sa = s3[j], sb = s3[j + 1];
      ushort4 ma = *(const ushort4*)(Axp + ((size_t)sa << 8) + lane * 4);
      ushort4 mb = *(const ushort4*)(Axp + ((size_t)sb << 8) + lane * 4);
      v.x += b2f(ma.x) + b2f(mb.x); v.y += b2f(ma.y) + b2f(mb.y);
      v.z += b2f(ma.z) + b2f(mb.z); v.w += b2f(ma.w) + b2f(mb.w);
      j += 2;
    }
    if (j < e) {
      int sa = s3[j];
      ushort4 ma = *(const ushort4*)(Axp + ((size_t)sa << 8) + lane * 4);
      v.x += b2f(ma.x); v.y += b2f(ma.y); v.z += b2f(ma.z); v.w += b2f(ma.w);
    }
    ushort4 o;
    o.x = f2b(v.x); o.y = f2b(v.y); o.z = f2b(v.z); o.w = f2b(v.w);
    *(ushort4*)(agg_wr + ((size_t)r << 8) + lane * 4) = o;
  }
}

// ------------- final GEMM: out = [A0|A1|A2] @ [B0;B1;B2] + row/col bias, ELU -------------
// 128x128 tile, BK=64, 4 waves (2x2), wave tile 64x64. All-bf16 A operands.
template <int NKT>
__device__ __forceinline__ void gemm_final_body(
    uint8_t* lds,
    const unsigned short* __restrict__ A0, const unsigned short* __restrict__ A1,
    const unsigned short* __restrict__ A2,
    const unsigned short* __restrict__ B0, const unsigned short* __restrict__ B1,
    const unsigned short* __restrict__ B2,
    const float* __restrict__ bias0, const float* __restrict__ bias1,
    const float* __restrict__ bias2,
    const float* __restrict__ rs1, const float* __restrict__ rs2,
    float* __restrict__ outp, int M, int row0, int n0, int tid) {
  uint8_t* ldsA = lds;            // 16 KB
  uint8_t* ldsB = lds + 16384;    // 16 KB
  const int lane = tid & 63;
  const int w = tid >> 6;
  const int wr = w >> 1, wc = w & 1;

  f32x4 acc[4][4] = {};

  for (int kt = 0; kt < NKT; ++kt) {
    const int kk = (kt & 3) << 6;
    const int sel = kt >> 2;
    const unsigned short* B = sel == 0 ? B0 : (sel == 1 ? B1 : B2);
    const unsigned short* A = sel == 0 ? A0 : (sel == 1 ? A1 : A2);
#pragma unroll
    for (int c = 0; c < 4; ++c) {
      int qq = c * 256 + tid;
      int row = qq >> 3, ch = qq & 7;
      int lch = ch ^ (row & 7);
      load_lds16(B + (size_t)(n0 + row) * 256 + kk + lch * 8, ldsB + qq * 16);
    }
#pragma unroll
    for (int c = 0; c < 4; ++c) {
      int qq = c * 256 + tid;
      int row = qq >> 3, ch = qq & 7;
      int lch = ch ^ (row & 7);
      int ar = row0 + row;
      if (ar >= M) ar = M - 1;
      load_lds16(A + (size_t)ar * 256 + kk + lch * 8, ldsA + qq * 16);
    }
    asm volatile("s_waitcnt vmcnt(0)" ::: "memory");
    __syncthreads();

#pragma unroll
    for (int s = 0; s < 2; ++s) {
      const int cbase = (s << 2) + (lane >> 4);
      short8 av[4];
#pragma unroll
      for (int m = 0; m < 4; ++m) {
        int rrow = wr * 64 + m * 16 + (lane & 15);
        av[m] = *(const short8*)(ldsA + rrow * 128 + ((cbase ^ (rrow & 7)) << 4));
      }
      short8 bv[4];
#pragma unroll
      for (int n = 0; n < 4; ++n) {
        int cc = wc * 64 + n * 16 + (lane & 15);
        bv[n] = *(const short8*)(ldsB + cc * 128 + ((cbase ^ (cc & 7)) << 4));
      }
#pragma unroll
      for (int m = 0; m < 4; ++m)
#pragma unroll
        for (int n = 0; n < 4; ++n)
          acc[m][n] = __builtin_amdgcn_mfma_f32_16x16x32_bf16(av[m], bv[n],
                                                              acc[m][n], 0, 0, 0);
    }
    __syncthreads();
  }

  // epilogue: combined bias + ELU, single f32 store
  float c0[4], c1v[4], c2v[4];
#pragma unroll
  for (int n = 0; n < 4; ++n) {
    int col = n0 + wc * 64 + n * 16 + (lane & 15);
    c0[n] = bias0[col];
    c1v[n] = bias1[col];
    c2v[n] = bias2 ? bias2[col] : 0.f;
  }
#pragma unroll
  for (int m = 0; m < 4; ++m) {
#pragma unroll
    for (int j = 0; j < 4; ++j) {
      int row = row0 + wr * 64 + m * 16 + (lane >> 4) * 4 + j;
      if (row < M) {
        float r1 = rs1[row];
        float r2 = rs2 ? rs2[row] : 0.f;
#pragma unroll
        for (int n = 0; n < 4; ++n) {
          int col = n0 + wc * 64 + n * 16 + (lane & 15);
          float v = acc[m][n][j] + c0[n] + r1 * c1v[n] + r2 * c2v[n];
          outp[(size_t)row * 256 + col] = elu1(v);
        }
      }
    }
  }
}

__global__ __launch_bounds__(256, 3) void gemm_final(
    const unsigned short* __restrict__ Axp, const unsigned short* __restrict__ Axa,
    const unsigned short* __restrict__ agg_c, const unsigned short* __restrict__ agg_w,
    const unsigned short* __restrict__ agg_wr,
    const unsigned short* __restrict__ WT_sp, const unsigned short* __restrict__ WT_c,
    const unsigned short* __restrict__ WT_w, const unsigned short* __restrict__ WT_sa,
    const unsigned short* __restrict__ WT_wr,
    const float* __restrict__ b_sp, const float* __restrict__ b_c,
    const float* __restrict__ b_w, const float* __restrict__ b_sa,
    const float* __restrict__ b_wr,
    const float* __restrict__ wdeg, const float* __restrict__ cntw_f,
    const float* __restrict__ cntwr_f,
    float* __restrict__ out_p, float* __restrict__ out_a,
    int Mp, int Ma, int nwgp, int nwg) {
  __shared__ uint8_t lds[32768];
  // bijective XCD swizzle (m204)
  const int orig = blockIdx.x;
  const int q = nwg >> 3, r = nwg & 7;
  const int xcd = orig & 7, idx = orig >> 3;
  const int wgid = (xcd < r ? xcd * (q + 1) : r * (q + 1) + (xcd - r) * q) + idx;
  const int tid = threadIdx.x;
  if (wgid < nwgp) {
    gemm_final_body<12>(lds, Axp, agg_c, agg_w,
                        WT_sp, WT_c, WT_w,
                        b_sp, b_c, b_w, wdeg, cntw_f,
                        out_p, Mp, (wgid >> 1) * 128, (wgid & 1) * 128, tid);
  } else {
    int w2 = wgid - nwgp;
    gemm_final_body<8>(lds, Axa, agg_wr, nullptr,
                       WT_sa, WT_wr, nullptr,
                       b_sa, b_wr, nullptr, cntwr_f, nullptr,
                       out_a, Ma, (w2 >> 1) * 128, (w2 & 1) * 128, tid);
  }
}

extern "C" void kernel_launch(void* const* d_in, const int* in_sizes, int n_in,
                              void* d_out, int out_size, void* d_ws, size_t ws_size,
                              hipStream_t stream) {
  const float* x_p = (const float*)d_in[0];
  const float* x_a = (const float*)d_in[1];
  const int* c_src = (const int*)d_in[2];
  const int* c_dst = (const int*)d_in[3];
  const float* c_w = (const float*)d_in[4];
  const int* w_src = (const int*)d_in[5];
  const int* w_dst = (const int*)d_in[6];
  const int* wr_src = (const int*)d_in[7];
  const int* wr_dst = (const int*)d_in[8];
  const float* W_sp = (const float*)d_in[9];
  const float* b_sp = (const float*)d_in[10];
  const float* W_sa = (const float*)d_in[11];
  const float* b_sa = (const float*)d_in[12];
  const float* W_c  = (const float*)d_in[13];
  const float* b_c  = (const float*)d_in[14];
  const float* W_w  = (const float*)d_in[15];
  const float* b_w  = (const float*)d_in[16];
  const float* W_wr = (const float*)d_in[17];
  const float* b_wr = (const float*)d_in[18];

  const int Mp = in_sizes[0] / 256;
  const int Ma = in_sizes[1] / 256;
  const int Ec = in_sizes[2], Ew = in_sizes[5], Ewr = in_sizes[7];

  // ---- workspace bump allocator (256B aligned); total ~216 MB ----
  size_t wo = 0;
  auto alloc = [&](size_t bytes) -> void* {
    void* p = (char*)d_ws + wo;
    wo += (bytes + 255) & ~(size_t)255;
    return p;
  };
  unsigned short* Axp    = (unsigned short*)alloc((size_t)Mp * 512);  // bf16 x_p
  unsigned short* Axa    = (unsigned short*)alloc((size_t)Ma * 512);  // bf16 x_a
  unsigned short* agg_c  = (unsigned short*)alloc((size_t)Mp * 512);
  unsigned short* agg_w  = (unsigned short*)alloc((size_t)Mp * 512);
  unsigned short* agg_wr = (unsigned short*)alloc((size_t)Ma * 512);
  unsigned short* WT_sp = (unsigned short*)alloc(131072);
  unsigned short* WT_sa = (unsigned short*)alloc(131072);
  unsigned short* WT_c  = (unsigned short*)alloc(131072);
  unsigned short* WT_w  = (unsigned short*)alloc(131072);
  unsigned short* WT_wr = (unsigned short*)alloc(131072);
  int* cnt_c  = (int*)alloc((size_t)((Mp + 1) + (Mp + 1) + (Ma + 1)) * 4);
  int* cnt_w  = cnt_c + (Mp + 1);
  int* cnt_wr = cnt_w + (Mp + 1);
  size_t cnt_bytes = (size_t)((Mp + 1) + (Mp + 1) + (Ma + 1)) * 4;
  int* off_c  = (int*)alloc((size_t)(Mp + 1) * 4);
  int* pos_c  = (int*)alloc((size_t)(Mp + 1) * 4);
  int* off_w  = (int*)alloc((size_t)(Mp + 1) * 4);
  int* pos_w  = (int*)alloc((size_t)(Mp + 1) * 4);
  int* off_wr = (int*)alloc((size_t)(Ma + 1) * 4);
  int* pos_wr = (int*)alloc((size_t)(Ma + 1) * 4);
  int* srcs_c  = (int*)alloc((size_t)Ec * 4);
  float* wgts_c = (float*)alloc((size_t)Ec * 4);
  int* srcs_w  = (int*)alloc((size_t)Ew * 4);
  int* srcs_wr = (int*)alloc((size_t)Ewr * 4);
  int* bsum = (int*)alloc(3 * 512 * 4);
  float* wdeg = (float*)alloc((size_t)Mp * 4);
  float* cntw_f = (float*)alloc((size_t)(Mp + 1) * 4);
  float* cntwr_f = (float*)alloc((size_t)(Ma + 1) * 4);

  float* out_p = (float*)d_out;
  float* out_a = (float*)d_out + (size_t)Mp * 256;

  // ---- prep (1 dispatch): cvt (x_p + x_a) || transposes || hist ----
  hipMemsetAsync(cnt_c, 0, cnt_bytes, stream);
  prep_all<<<NB_CVT + NB_T + NB_H, 256, 0, stream>>>(
      (const float4*)x_p, (ushort4*)Axp, Mp * 64,
      (const float4*)x_a, (ushort4*)Axa, Ma * 64,
      W_sp, W_sa, W_c, W_w, W_wr,
      WT_sp, WT_sa, WT_c, WT_w, WT_wr,
      c_dst, Ec, cnt_c, w_dst, Ew, cnt_w, wr_dst, Ewr, cnt_wr);

  // ---- CSR scans + bucket (cnt->float folded into addoff3) ----
  const int ns1 = Mp + 1, ns2 = Mp + 1, ns3 = Ma + 1;
  const int B1 = (ns1 + 511) / 512, B2 = (ns2 + 511) / 512, B3 = (ns3 + 511) / 512;
  const int Bmax = B1 > B2 ? (B1 > B3 ? B1 : B3) : (B2 > B3 ? B2 : B3);
  {
    dim3 g(Bmax, 3);
    scan512_3<<<g, 512, 0, stream>>>(cnt_c, off_c, ns1, cnt_w, off_w, ns2,
                                     cnt_wr, off_wr, ns3, bsum);
    scan_bsums3<<<3, 512, 0, stream>>>(bsum, B1, B2, B3);
    addoff3<<<g, 512, 0, stream>>>(off_c, pos_c, ns1, off_w, pos_w, ns2,
                                   off_wr, pos_wr, ns3, bsum,
                                   cnt_w, cntw_f, cnt_wr, cntwr_f);
  }
  bucket3<<<256, 256, 0, stream>>>(c_dst, c_src, c_w, Ec, pos_c, srcs_c, wgts_c,
                                   w_dst, w_src, Ew, pos_w, srcs_w,
                                   wr_dst, wr_src, Ewr, pos_wr, srcs_wr);

  // ---- feature aggregation (relation-split waves) ----
  {
    int totalWaves = 2 * Mp + Ma;
    aggregate3<<<(totalWaves + 3) / 4, 256, 0, stream>>>(
        Axp, Axa, Mp, Ma,
        off_c, srcs_c, wgts_c, off_w, srcs_w, off_wr, srcs_wr,
        agg_c, agg_w, agg_wr, wdeg);
  }

  // ---- final fused GEMM (K=768 paper / K=512 author) + bias + ELU ----
  {
    const int nsp = (Mp + 127) / 128, nsa = (Ma + 127) / 128;
    const int nwgp = nsp * 2, nwga = nsa * 2;
    gemm_final<<<nwgp + nwga, 256, 0, stream>>>(
        Axp, Axa, agg_c, agg_w, agg_wr,
        WT_sp, WT_c, WT_w, WT_sa, WT_wr,
        b_sp, b_c, b_w, b_sa, b_wr,
        wdeg, cntw_f, cntwr_f,
        out_p, out_a, Mp, Ma, nwgp, nwgp + nwga);
  }
}

// Round 25
// 308.249 us; speedup vs baseline: 1.0375x; 1.0122x over previous
//
#include <hip/hip_runtime.h>
#include <stdint.h>

typedef __attribute__((ext_vector_type(8))) short short8;
typedef __attribute__((ext_vector_type(4))) float f32x4;

__device__ __forceinline__ unsigned short f2b(float f) {
  union { float f; uint32_t u; } v; v.f = f;
  uint32_t r = (v.u + 0x7fffu + ((v.u >> 16) & 1u)) >> 16;
  return (unsigned short)r;
}
__device__ __forceinline__ float b2f(unsigned short h) {
  union { uint32_t u; float f; } v; v.u = ((uint32_t)h) << 16; return v.f;
}

__device__ __forceinline__ void load_lds16(const void* g, void* l) {
  __builtin_amdgcn_global_load_lds(
      (const __attribute__((address_space(1))) uint32_t*)g,
      (__attribute__((address_space(3))) uint32_t*)l, 16, 0, 0);
}

__device__ __forceinline__ float elu1(float v) {
  return v > 0.f ? v : expf(v) - 1.f;
}

// ------------- merged prep: cvt (x_p,x_a->bf16) || 5x transpose+cast || hist3 -------------
#define NB_CVT 1024
#define NB_T 320
#define NB_H 256
__global__ void prep_all(
    const float4* __restrict__ xp_in, ushort4* __restrict__ xp_out, int n4p,
    const float4* __restrict__ xa_in, ushort4* __restrict__ xa_out, int n4a,
    const float* __restrict__ W0, const float* __restrict__ W1,
    const float* __restrict__ W2, const float* __restrict__ W3,
    const float* __restrict__ W4,
    unsigned short* __restrict__ T0, unsigned short* __restrict__ T1,
    unsigned short* __restrict__ T2, unsigned short* __restrict__ T3,
    unsigned short* __restrict__ T4,
    const int* __restrict__ d1, int E1, int* __restrict__ c1,
    const int* __restrict__ d2, int E2, int* __restrict__ c2,
    const int* __restrict__ d3, int E3, int* __restrict__ c3) {
  __shared__ unsigned short t[32][33];
  const int bid = blockIdx.x;
  if (bid < NB_CVT) {
    int i = bid * blockDim.x + threadIdx.x;
    int stride = NB_CVT * blockDim.x;
    int tot = n4p + n4a;
    for (; i < tot; i += stride) {
      const float4 f = (i < n4p) ? xp_in[i] : xa_in[i - n4p];
      ushort4 o;
      o.x = f2b(f.x); o.y = f2b(f.y); o.z = f2b(f.z); o.w = f2b(f.w);
      if (i < n4p) xp_out[i] = o;
      else xa_out[i - n4p] = o;
    }
  } else if (bid < NB_CVT + NB_T) {
    int local = bid - NB_CVT;
    int mat = local >> 6, bt = local & 63;
    const float* W; unsigned short* T;
    switch (mat) {
      case 0: W = W0; T = T0; break;
      case 1: W = W1; T = T1; break;
      case 2: W = W2; T = T2; break;
      case 3: W = W3; T = T3; break;
      default: W = W4; T = T4; break;
    }
    int bx = bt & 7, by = bt >> 3;
    int x = threadIdx.x & 31, y = threadIdx.x >> 5;  // 32x8
    for (int i = 0; i < 32; i += 8)
      t[y + i][x] = f2b(W[(by * 32 + y + i) * 256 + bx * 32 + x]);
    __syncthreads();
    for (int i = 0; i < 32; i += 8)
      T[(bx * 32 + y + i) * 256 + by * 32 + x] = t[x][y + i];
  } else {
    int local = bid - NB_CVT - NB_T;
    int i = local * blockDim.x + threadIdx.x;
    int stride = NB_H * blockDim.x;
    int tot = E1 + E2 + E3;
    for (; i < tot; i += stride) {
      if (i < E1) atomicAdd(&c1[d1[i]], 1);
      else if (i < E1 + E2) atomicAdd(&c2[d2[i - E1]], 1);
      else atomicAdd(&c3[d3[i - E1 - E2]], 1);
    }
  }
}

// ------------- CSR scans + bucket -------------
__global__ void scan512_3(const int* __restrict__ c1, int* __restrict__ o1, int ns1,
                          const int* __restrict__ c2, int* __restrict__ o2, int ns2,
                          const int* __restrict__ c3, int* __restrict__ o3, int ns3,
                          int* __restrict__ bsum) {
  const int* in; int* out; int ns;
  switch (blockIdx.y) {
    case 0: in = c1; out = o1; ns = ns1; break;
    case 1: in = c2; out = o2; ns = ns2; break;
    default: in = c3; out = o3; ns = ns3; break;
  }
  if ((int)blockIdx.x * 512 >= ns) return;
  __shared__ int s[512];
  int t = threadIdx.x;
  int i = blockIdx.x * 512 + t;
  int v = (i < ns) ? in[i] : 0;
  s[t] = v;
  __syncthreads();
  for (int off = 1; off < 512; off <<= 1) {
    int x = s[t];
    int y = (t >= off) ? s[t - off] : 0;
    __syncthreads();
    s[t] = x + y;
    __syncthreads();
  }
  if (i < ns) out[i] = s[t] - v;  // exclusive
  if (t == 511) bsum[blockIdx.y * 512 + blockIdx.x] = s[511];
}

__global__ void scan_bsums3(int* __restrict__ bsum, int B1, int B2, int B3) {
  int rel = blockIdx.x;
  int B = rel == 0 ? B1 : (rel == 1 ? B2 : B3);
  int* bs = bsum + rel * 512;
  __shared__ int s[512];
  int t = threadIdx.x;
  int v = (t < B) ? bs[t] : 0;
  s[t] = v;
  __syncthreads();
  for (int off = 1; off < 512; off <<= 1) {
    int x = s[t];
    int y = (t >= off) ? s[t - off] : 0;
    __syncthreads();
    s[t] = x + y;
    __syncthreads();
  }
  if (t < B) bs[t] = s[t] - v;  // exclusive
}

// add block offsets; seed pos[]; also emit float counts for rel2/rel3
__global__ void addoff3(int* __restrict__ o1, int* __restrict__ p1, int ns1,
                        int* __restrict__ o2, int* __restrict__ p2, int ns2,
                        int* __restrict__ o3, int* __restrict__ p3, int ns3,
                        const int* __restrict__ bsum,
                        const int* __restrict__ c2, float* __restrict__ f2,
                        const int* __restrict__ c3, float* __restrict__ f3) {
  int* o; int* p; int ns;
  switch (blockIdx.y) {
    case 0: o = o1; p = p1; ns = ns1; break;
    case 1: o = o2; p = p2; ns = ns2; break;
    default: o = o3; p = p3; ns = ns3; break;
  }
  int i = blockIdx.x * 512 + threadIdx.x;
  if (i < ns) {
    int v = o[i] + bsum[blockIdx.y * 512 + blockIdx.x];
    o[i] = v;
    p[i] = v;
    if (blockIdx.y == 1) f2[i] = (float)c2[i];
    else if (blockIdx.y == 2) f3[i] = (float)c3[i];
  }
}

__global__ void bucket3(
    const int* __restrict__ d1, const int* __restrict__ s1in,
    const float* __restrict__ w1in, int E1, int* __restrict__ p1,
    int* __restrict__ s1, float* __restrict__ w1,
    const int* __restrict__ d2, const int* __restrict__ s2in, int E2,
    int* __restrict__ p2, int* __restrict__ s2,
    const int* __restrict__ d3, const int* __restrict__ s3in, int E3,
    int* __restrict__ p3, int* __restrict__ s3) {
  int i = blockIdx.x * blockDim.x + threadIdx.x;
  int stride = gridDim.x * blockDim.x;
  int tot = E1 + E2 + E3;
  for (; i < tot; i += stride) {
    if (i < E1) {
      int p = atomicAdd(&p1[d1[i]], 1);
      s1[p] = s1in[i];
      w1[p] = w1in[i];
    } else if (i < E1 + E2) {
      int k = i - E1;
      int p = atomicAdd(&p2[d2[k]], 1);
      s2[p] = s2in[k];
    } else {
      int k = i - E1 - E2;
      int p = atomicAdd(&p3[d3[k]], 1);
      s3[p] = s3in[k];
    }
  }
}

// ------------- feature aggregation (1 wave per dst row, all-bf16 gathers) -------------
__global__ void aggregate3(
    const unsigned short* __restrict__ Axp, const unsigned short* __restrict__ Axa,
    int Np, int Na,
    const int* __restrict__ off1, const int* __restrict__ s1,
    const float* __restrict__ w1,
    const int* __restrict__ off2, const int* __restrict__ s2,
    const int* __restrict__ off3, const int* __restrict__ s3,
    unsigned short* __restrict__ agg_c, unsigned short* __restrict__ agg_w,
    unsigned short* __restrict__ agg_wr, float* __restrict__ wdeg) {
  int gw = (blockIdx.x * blockDim.x + threadIdx.x) >> 6;
  int lane = threadIdx.x & 63;
  if (gw < Np) {
    float4 vc = {0.f, 0.f, 0.f, 0.f};
    float4 vw = {0.f, 0.f, 0.f, 0.f};
    float wd = 0.f;
    int j1 = off1[gw], e1 = off1[gw + 1];
    int j2 = off2[gw], e2 = off2[gw + 1];
    // merged main loop: 2 cites + 2 writes gathers in flight together
    while (j1 + 2 <= e1 && j2 + 2 <= e2) {
      int sa = s1[j1], sb = s1[j1 + 1];
      float wa = w1[j1], wb = w1[j1 + 1];
      int sc = s2[j2], sd = s2[j2 + 1];
      ushort4 ma = *(const ushort4*)(Axp + ((size_t)sa << 8) + lane * 4);
      ushort4 mb = *(const ushort4*)(Axp + ((size_t)sb << 8) + lane * 4);
      ushort4 mc = *(const ushort4*)(Axa + ((size_t)sc << 8) + lane * 4);
      ushort4 md = *(const ushort4*)(Axa + ((size_t)sd << 8) + lane * 4);
      vc.x += wa * b2f(ma.x) + wb * b2f(mb.x);
      vc.y += wa * b2f(ma.y) + wb * b2f(mb.y);
      vc.z += wa * b2f(ma.z) + wb * b2f(mb.z);
      vc.w += wa * b2f(ma.w) + wb * b2f(mb.w);
      vw.x += b2f(mc.x) + b2f(md.x); vw.y += b2f(mc.y) + b2f(md.y);
      vw.z += b2f(mc.z) + b2f(md.z); vw.w += b2f(mc.w) + b2f(md.w);
      wd += wa + wb;
      j1 += 2; j2 += 2;
    }
    // 2-wide tails (2 independent gathers in flight)
    for (; j1 + 2 <= e1; j1 += 2) {
      int sa = s1[j1], sb = s1[j1 + 1];
      float wa = w1[j1], wb = w1[j1 + 1];
      ushort4 ma = *(const ushort4*)(Axp + ((size_t)sa << 8) + lane * 4);
      ushort4 mb = *(const ushort4*)(Axp + ((size_t)sb << 8) + lane * 4);
      vc.x += wa * b2f(ma.x) + wb * b2f(mb.x);
      vc.y += wa * b2f(ma.y) + wb * b2f(mb.y);
      vc.z += wa * b2f(ma.z) + wb * b2f(mb.z);
      vc.w += wa * b2f(ma.w) + wb * b2f(mb.w);
      wd += wa + wb;
    }
    if (j1 < e1) {
      int sa = s1[j1];
      float wa = w1[j1];
      ushort4 ma = *(const ushort4*)(Axp + ((size_t)sa << 8) + lane * 4);
      vc.x += wa * b2f(ma.x); vc.y += wa * b2f(ma.y);
      vc.z += wa * b2f(ma.z); vc.w += wa * b2f(ma.w);
      wd += wa;
    }
    for (; j2 + 2 <= e2; j2 += 2) {
      int sc = s2[j2], sd = s2[j2 + 1];
      ushort4 mc = *(const ushort4*)(Axa + ((size_t)sc << 8) + lane * 4);
      ushort4 md = *(const ushort4*)(Axa + ((size_t)sd << 8) + lane * 4);
      vw.x += b2f(mc.x) + b2f(md.x); vw.y += b2f(mc.y) + b2f(md.y);
      vw.z += b2f(mc.z) + b2f(md.z); vw.w += b2f(mc.w) + b2f(md.w);
    }
    if (j2 < e2) {
      int sc = s2[j2];
      ushort4 mc = *(const ushort4*)(Axa + ((size_t)sc << 8) + lane * 4);
      vw.x += b2f(mc.x); vw.y += b2f(mc.y);
      vw.z += b2f(mc.z); vw.w += b2f(mc.w);
    }
    ushort4 oc, ow;
    oc.x = f2b(vc.x); oc.y = f2b(vc.y); oc.z = f2b(vc.z); oc.w = f2b(vc.w);
    ow.x = f2b(vw.x); ow.y = f2b(vw.y); ow.z = f2b(vw.z); ow.w = f2b(vw.w);
    *(ushort4*)(agg_c + ((size_t)gw << 8) + lane * 4) = oc;
    *(ushort4*)(agg_w + ((size_t)gw << 8) + lane * 4) = ow;
    if (lane == 0) wdeg[gw] = wd;
  } else if (gw < Np + Na) {
    int r = gw - Np;
    float4 v = {0.f, 0.f, 0.f, 0.f};
    int j = off3[r], e = off3[r + 1];
    for (; j + 4 <= e; j += 4) {
      int sa = s3[j], sb = s3[j + 1], sc = s3[j + 2], sd = s3[j + 3];
      ushort4 ma = *(const ushort4*)(Axp + ((size_t)sa << 8) + lane * 4);
      ushort4 mb = *(const ushort4*)(Axp + ((size_t)sb << 8) + lane * 4);
      ushort4 mc = *(const ushort4*)(Axp + ((size_t)sc << 8) + lane * 4);
      ushort4 md = *(const ushort4*)(Axp + ((size_t)sd << 8) + lane * 4);
      v.x += b2f(ma.x) + b2f(mb.x) + b2f(mc.x) + b2f(md.x);
      v.y += b2f(ma.y) + b2f(mb.y) + b2f(mc.y) + b2f(md.y);
      v.z += b2f(ma.z) + b2f(mb.z) + b2f(mc.z) + b2f(md.z);
      v.w += b2f(ma.w) + b2f(mb.w) + b2f(mc.w) + b2f(md.w);
    }
    if (j + 2 <= e) {
      int sa = s3[j], sb = s3[j + 1];
      ushort4 ma = *(const ushort4*)(Axp + ((size_t)sa << 8) + lane * 4);
      ushort4 mb = *(const ushort4*)(Axp + ((size_t)sb << 8) + lane * 4);
      v.x += b2f(ma.x) + b2f(mb.x); v.y += b2f(ma.y) + b2f(mb.y);
      v.z += b2f(ma.z) + b2f(mb.z); v.w += b2f(ma.w) + b2f(mb.w);
      j += 2;
    }
    if (j < e) {
      int sa = s3[j];
      ushort4 ma = *(const ushort4*)(Axp + ((size_t)sa << 8) + lane * 4);
      v.x += b2f(ma.x); v.y += b2f(ma.y); v.z += b2f(ma.z); v.w += b2f(ma.w);
    }
    ushort4 o;
    o.x = f2b(v.x); o.y = f2b(v.y); o.z = f2b(v.z); o.w = f2b(v.w);
    *(ushort4*)(agg_wr + ((size_t)r << 8) + lane * 4) = o;
  }
}

// ------------- final GEMM: out = [A0|A1|A2] @ [B0;B1;B2] + row/col bias, ELU -------------
// 128x128 tile, BK=64, 4 waves (2x2), wave tile 64x64. All-bf16 A operands.
template <int NKT>
__device__ __forceinline__ void gemm_final_body(
    uint8_t* lds,
    const unsigned short* __restrict__ A0, const unsigned short* __restrict__ A1,
    const unsigned short* __restrict__ A2,
    const unsigned short* __restrict__ B0, const unsigned short* __restrict__ B1,
    const unsigned short* __restrict__ B2,
    const float* __restrict__ bias0, const float* __restrict__ bias1,
    const float* __restrict__ bias2,
    const float* __restrict__ rs1, const float* __restrict__ rs2,
    float* __restrict__ outp, int M, int row0, int n0, int tid) {
  uint8_t* ldsA = lds;            // 16 KB
  uint8_t* ldsB = lds + 16384;    // 16 KB
  const int lane = tid & 63;
  const int w = tid >> 6;
  const int wr = w >> 1, wc = w & 1;

  f32x4 acc[4][4] = {};

  for (int kt = 0; kt < NKT; ++kt) {
    const int kk = (kt & 3) << 6;
    const int sel = kt >> 2;
    const unsigned short* B = sel == 0 ? B0 : (sel == 1 ? B1 : B2);
    const unsigned short* A = sel == 0 ? A0 : (sel == 1 ? A1 : A2);
#pragma unroll
    for (int c = 0; c < 4; ++c) {
      int qq = c * 256 + tid;
      int row = qq >> 3, ch = qq & 7;
      int lch = ch ^ (row & 7);
      load_lds16(B + (size_t)(n0 + row) * 256 + kk + lch * 8, ldsB + qq * 16);
    }
#pragma unroll
    for (int c = 0; c < 4; ++c) {
      int qq = c * 256 + tid;
      int row = qq >> 3, ch = qq & 7;
      int lch = ch ^ (row & 7);
      int ar = row0 + row;
      if (ar >= M) ar = M - 1;
      load_lds16(A + (size_t)ar * 256 + kk + lch * 8, ldsA + qq * 16);
    }
    asm volatile("s_waitcnt vmcnt(0)" ::: "memory");
    __syncthreads();

#pragma unroll
    for (int s = 0; s < 2; ++s) {
      const int cbase = (s << 2) + (lane >> 4);
      short8 av[4];
#pragma unroll
      for (int m = 0; m < 4; ++m) {
        int rrow = wr * 64 + m * 16 + (lane & 15);
        av[m] = *(const short8*)(ldsA + rrow * 128 + ((cbase ^ (rrow & 7)) << 4));
      }
      short8 bv[4];
#pragma unroll
      for (int n = 0; n < 4; ++n) {
        int cc = wc * 64 + n * 16 + (lane & 15);
        bv[n] = *(const short8*)(ldsB + cc * 128 + ((cbase ^ (cc & 7)) << 4));
      }
#pragma unroll
      for (int m = 0; m < 4; ++m)
#pragma unroll
        for (int n = 0; n < 4; ++n)
          acc[m][n] = __builtin_amdgcn_mfma_f32_16x16x32_bf16(av[m], bv[n],
                                                              acc[m][n], 0, 0, 0);
    }
    __syncthreads();
  }

  // epilogue: combined bias + ELU, single f32 store
  float c0[4], c1v[4], c2v[4];
#pragma unroll
  for (int n = 0; n < 4; ++n) {
    int col = n0 + wc * 64 + n * 16 + (lane & 15);
    c0[n] = bias0[col];
    c1v[n] = bias1[col];
    c2v[n] = bias2 ? bias2[col] : 0.f;
  }
#pragma unroll
  for (int m = 0; m < 4; ++m) {
#pragma unroll
    for (int j = 0; j < 4; ++j) {
      int row = row0 + wr * 64 + m * 16 + (lane >> 4) * 4 + j;
      if (row < M) {
        float r1 = rs1[row];
        float r2 = rs2 ? rs2[row] : 0.f;
#pragma unroll
        for (int n = 0; n < 4; ++n) {
          int col = n0 + wc * 64 + n * 16 + (lane & 15);
          float v = acc[m][n][j] + c0[n] + r1 * c1v[n] + r2 * c2v[n];
          outp[(size_t)row * 256 + col] = elu1(v);
        }
      }
    }
  }
}

__global__ __launch_bounds__(256, 3) void gemm_final(
    const unsigned short* __restrict__ Axp, const unsigned short* __restrict__ Axa,
    const unsigned short* __restrict__ agg_c, const unsigned short* __restrict__ agg_w,
    const unsigned short* __restrict__ agg_wr,
    const unsigned short* __restrict__ WT_sp, const unsigned short* __restrict__ WT_c,
    const unsigned short* __restrict__ WT_w, const unsigned short* __restrict__ WT_sa,
    const unsigned short* __restrict__ WT_wr,
    const float* __restrict__ b_sp, const float* __restrict__ b_c,
    const float* __restrict__ b_w, const float* __restrict__ b_sa,
    const float* __restrict__ b_wr,
    const float* __restrict__ wdeg, const float* __restrict__ cntw_f,
    const float* __restrict__ cntwr_f,
    float* __restrict__ out_p, float* __restrict__ out_a,
    int Mp, int Ma, int nwgp, int nwg) {
  __shared__ uint8_t lds[32768];
  // bijective XCD swizzle (m204)
  const int orig = blockIdx.x;
  const int q = nwg >> 3, r = nwg & 7;
  const int xcd = orig & 7, idx = orig >> 3;
  const int wgid = (xcd < r ? xcd * (q + 1) : r * (q + 1) + (xcd - r) * q) + idx;
  const int tid = threadIdx.x;
  if (wgid < nwgp) {
    gemm_final_body<12>(lds, Axp, agg_c, agg_w,
                        WT_sp, WT_c, WT_w,
                        b_sp, b_c, b_w, wdeg, cntw_f,
                        out_p, Mp, (wgid >> 1) * 128, (wgid & 1) * 128, tid);
  } else {
    int w2 = wgid - nwgp;
    gemm_final_body<8>(lds, Axa, agg_wr, nullptr,
                       WT_sa, WT_wr, nullptr,
                       b_sa, b_wr, nullptr, cntwr_f, nullptr,
                       out_a, Ma, (w2 >> 1) * 128, (w2 & 1) * 128, tid);
  }
}

extern "C" void kernel_launch(void* const* d_in, const int* in_sizes, int n_in,
                              void* d_out, int out_size, void* d_ws, size_t ws_size,
                              hipStream_t stream) {
  const float* x_p = (const float*)d_in[0];
  const float* x_a = (const float*)d_in[1];
  const int* c_src = (const int*)d_in[2];
  const int* c_dst = (const int*)d_in[3];
  const float* c_w = (const float*)d_in[4];
  const int* w_src = (const int*)d_in[5];
  const int* w_dst = (const int*)d_in[6];
  const int* wr_src = (const int*)d_in[7];
  const int* wr_dst = (const int*)d_in[8];
  const float* W_sp = (const float*)d_in[9];
  const float* b_sp = (const float*)d_in[10];
  const float* W_sa = (const float*)d_in[11];
  const float* b_sa = (const float*)d_in[12];
  const float* W_c  = (const float*)d_in[13];
  const float* b_c  = (const float*)d_in[14];
  const float* W_w  = (const float*)d_in[15];
  const float* b_w  = (const float*)d_in[16];
  const float* W_wr = (const float*)d_in[17];
  const float* b_wr = (const float*)d_in[18];

  const int Mp = in_sizes[0] / 256;
  const int Ma = in_sizes[1] / 256;
  const int Ec = in_sizes[2], Ew = in_sizes[5], Ewr = in_sizes[7];

  // ---- workspace bump allocator (256B aligned); total ~216 MB ----
  size_t wo = 0;
  auto alloc = [&](size_t bytes) -> void* {
    void* p = (char*)d_ws + wo;
    wo += (bytes + 255) & ~(size_t)255;
    return p;
  };
  unsigned short* Axp    = (unsigned short*)alloc((size_t)Mp * 512);  // bf16 x_p
  unsigned short* Axa    = (unsigned short*)alloc((size_t)Ma * 512);  // bf16 x_a
  unsigned short* agg_c  = (unsigned short*)alloc((size_t)Mp * 512);
  unsigned short* agg_w  = (unsigned short*)alloc((size_t)Mp * 512);
  unsigned short* agg_wr = (unsigned short*)alloc((size_t)Ma * 512);
  unsigned short* WT_sp = (unsigned short*)alloc(131072);
  unsigned short* WT_sa = (unsigned short*)alloc(131072);
  unsigned short* WT_c  = (unsigned short*)alloc(131072);
  unsigned short* WT_w  = (unsigned short*)alloc(131072);
  unsigned short* WT_wr = (unsigned short*)alloc(131072);
  int* cnt_c  = (int*)alloc((size_t)((Mp + 1) + (Mp + 1) + (Ma + 1)) * 4);
  int* cnt_w  = cnt_c + (Mp + 1);
  int* cnt_wr = cnt_w + (Mp + 1);
  size_t cnt_bytes = (size_t)((Mp + 1) + (Mp + 1) + (Ma + 1)) * 4;
  int* off_c  = (int*)alloc((size_t)(Mp + 1) * 4);
  int* pos_c  = (int*)alloc((size_t)(Mp + 1) * 4);
  int* off_w  = (int*)alloc((size_t)(Mp + 1) * 4);
  int* pos_w  = (int*)alloc((size_t)(Mp + 1) * 4);
  int* off_wr = (int*)alloc((size_t)(Ma + 1) * 4);
  int* pos_wr = (int*)alloc((size_t)(Ma + 1) * 4);
  int* srcs_c  = (int*)alloc((size_t)Ec * 4);
  float* wgts_c = (float*)alloc((size_t)Ec * 4);
  int* srcs_w  = (int*)alloc((size_t)Ew * 4);
  int* srcs_wr = (int*)alloc((size_t)Ewr * 4);
  int* bsum = (int*)alloc(3 * 512 * 4);
  float* wdeg = (float*)alloc((size_t)Mp * 4);
  float* cntw_f = (float*)alloc((size_t)(Mp + 1) * 4);
  float* cntwr_f = (float*)alloc((size_t)(Ma + 1) * 4);

  float* out_p = (float*)d_out;
  float* out_a = (float*)d_out + (size_t)Mp * 256;

  // ---- prep (1 dispatch): cvt (x_p + x_a) || transposes || hist ----
  hipMemsetAsync(cnt_c, 0, cnt_bytes, stream);
  prep_all<<<NB_CVT + NB_T + NB_H, 256, 0, stream>>>(
      (const float4*)x_p, (ushort4*)Axp, Mp * 64,
      (const float4*)x_a, (ushort4*)Axa, Ma * 64,
      W_sp, W_sa, W_c, W_w, W_wr,
      WT_sp, WT_sa, WT_c, WT_w, WT_wr,
      c_dst, Ec, cnt_c, w_dst, Ew, cnt_w, wr_dst, Ewr, cnt_wr);

  // ---- CSR scans + bucket (cnt->float folded into addoff3) ----
  const int ns1 = Mp + 1, ns2 = Mp + 1, ns3 = Ma + 1;
  const int B1 = (ns1 + 511) / 512, B2 = (ns2 + 511) / 512, B3 = (ns3 + 511) / 512;
  const int Bmax = B1 > B2 ? (B1 > B3 ? B1 : B3) : (B2 > B3 ? B2 : B3);
  {
    dim3 g(Bmax, 3);
    scan512_3<<<g, 512, 0, stream>>>(cnt_c, off_c, ns1, cnt_w, off_w, ns2,
                                     cnt_wr, off_wr, ns3, bsum);
    scan_bsums3<<<3, 512, 0, stream>>>(bsum, B1, B2, B3);
    addoff3<<<g, 512, 0, stream>>>(off_c, pos_c, ns1, off_w, pos_w, ns2,
                                   off_wr, pos_wr, ns3, bsum,
                                   cnt_w, cntw_f, cnt_wr, cntwr_f);
  }
  bucket3<<<256, 256, 0, stream>>>(c_dst, c_src, c_w, Ec, pos_c, srcs_c, wgts_c,
                                   w_dst, w_src, Ew, pos_w, srcs_w,
                                   wr_dst, wr_src, Ewr, pos_wr, srcs_wr);

  // ---- feature aggregation (all-bf16 gathers, 2-wide tails) ----
  {
    int totalWaves = Mp + Ma;
    aggregate3<<<(totalWaves + 3) / 4, 256, 0, stream>>>(
        Axp, Axa, Mp, Ma,
        off_c, srcs_c, wgts_c, off_w, srcs_w, off_wr, srcs_wr,
        agg_c, agg_w, agg_wr, wdeg);
  }

  // ---- final fused GEMM (K=768 paper / K=512 author) + bias + ELU ----
  {
    const int nsp = (Mp + 127) / 128, nsa = (Ma + 127) / 128;
    const int nwgp = nsp * 2, nwga = nsa * 2;
    gemm_final<<<nwgp + nwga, 256, 0, stream>>>(
        Axp, Axa, agg_c, agg_w, agg_wr,
        WT_sp, WT_c, WT_w, WT_sa, WT_wr,
        b_sp, b_c, b_w, b_sa, b_wr,
        wdeg, cntw_f, cntwr_f,
        out_p, out_a, Mp, Ma, nwgp, nwgp + nwga);
  }
}

// Round 26
// 298.589 us; speedup vs baseline: 1.0711x; 1.0324x over previous
//
#include <hip/hip_runtime.h>
#include <stdint.h>

typedef __attribute__((ext_vector_type(8))) short short8;
typedef __attribute__((ext_vector_type(4))) float f32x4;

__device__ __forceinline__ unsigned short f2b(float f) {
  union { float f; uint32_t u; } v; v.f = f;
  uint32_t r = (v.u + 0x7fffu + ((v.u >> 16) & 1u)) >> 16;
  return (unsigned short)r;
}
__device__ __forceinline__ float b2f(unsigned short h) {
  union { uint32_t u; float f; } v; v.u = ((uint32_t)h) << 16; return v.f;
}

__device__ __forceinline__ void load_lds16(const void* g, void* l) {
  __builtin_amdgcn_global_load_lds(
      (const __attribute__((address_space(1))) uint32_t*)g,
      (__attribute__((address_space(3))) uint32_t*)l, 16, 0, 0);
}

__device__ __forceinline__ float elu1(float v) {
  return v > 0.f ? v : expf(v) - 1.f;
}

// ------------- merged prep: cvt (x_p,x_a->bf16) || 5x transpose+cast || hist3 -------------
#define NB_CVT 1024
#define NB_T 320
#define NB_H 256
__global__ void prep_all(
    const float4* __restrict__ xp_in, ushort4* __restrict__ xp_out, int n4p,
    const float4* __restrict__ xa_in, ushort4* __restrict__ xa_out, int n4a,
    const float* __restrict__ W0, const float* __restrict__ W1,
    const float* __restrict__ W2, const float* __restrict__ W3,
    const float* __restrict__ W4,
    unsigned short* __restrict__ T0, unsigned short* __restrict__ T1,
    unsigned short* __restrict__ T2, unsigned short* __restrict__ T3,
    unsigned short* __restrict__ T4,
    const int* __restrict__ d1, int E1, int* __restrict__ c1,
    const int* __restrict__ d2, int E2, int* __restrict__ c2,
    const int* __restrict__ d3, int E3, int* __restrict__ c3) {
  __shared__ unsigned short t[32][33];
  const int bid = blockIdx.x;
  if (bid < NB_CVT) {
    int i = bid * blockDim.x + threadIdx.x;
    int stride = NB_CVT * blockDim.x;
    int tot = n4p + n4a;
    for (; i < tot; i += stride) {
      const float4 f = (i < n4p) ? xp_in[i] : xa_in[i - n4p];
      ushort4 o;
      o.x = f2b(f.x); o.y = f2b(f.y); o.z = f2b(f.z); o.w = f2b(f.w);
      if (i < n4p) xp_out[i] = o;
      else xa_out[i - n4p] = o;
    }
  } else if (bid < NB_CVT + NB_T) {
    int local = bid - NB_CVT;
    int mat = local >> 6, bt = local & 63;
    const float* W; unsigned short* T;
    switch (mat) {
      case 0: W = W0; T = T0; break;
      case 1: W = W1; T = T1; break;
      case 2: W = W2; T = T2; break;
      case 3: W = W3; T = T3; break;
      default: W = W4; T = T4; break;
    }
    int bx = bt & 7, by = bt >> 3;
    int x = threadIdx.x & 31, y = threadIdx.x >> 5;  // 32x8
    for (int i = 0; i < 32; i += 8)
      t[y + i][x] = f2b(W[(by * 32 + y + i) * 256 + bx * 32 + x]);
    __syncthreads();
    for (int i = 0; i < 32; i += 8)
      T[(bx * 32 + y + i) * 256 + by * 32 + x] = t[x][y + i];
  } else {
    int local = bid - NB_CVT - NB_T;
    int i = local * blockDim.x + threadIdx.x;
    int stride = NB_H * blockDim.x;
    int tot = E1 + E2 + E3;
    for (; i < tot; i += stride) {
      if (i < E1) atomicAdd(&c1[d1[i]], 1);
      else if (i < E1 + E2) atomicAdd(&c2[d2[i - E1]], 1);
      else atomicAdd(&c3[d3[i - E1 - E2]], 1);
    }
  }
}

// ------------- CSR scans + bucket -------------
__global__ void scan512_3(const int* __restrict__ c1, int* __restrict__ o1, int ns1,
                          const int* __restrict__ c2, int* __restrict__ o2, int ns2,
                          const int* __restrict__ c3, int* __restrict__ o3, int ns3,
                          int* __restrict__ bsum) {
  const int* in; int* out; int ns;
  switch (blockIdx.y) {
    case 0: in = c1; out = o1; ns = ns1; break;
    case 1: in = c2; out = o2; ns = ns2; break;
    default: in = c3; out = o3; ns = ns3; break;
  }
  if ((int)blockIdx.x * 512 >= ns) return;
  __shared__ int s[512];
  int t = threadIdx.x;
  int i = blockIdx.x * 512 + t;
  int v = (i < ns) ? in[i] : 0;
  s[t] = v;
  __syncthreads();
  for (int off = 1; off < 512; off <<= 1) {
    int x = s[t];
    int y = (t >= off) ? s[t - off] : 0;
    __syncthreads();
    s[t] = x + y;
    __syncthreads();
  }
  if (i < ns) out[i] = s[t] - v;  // exclusive
  if (t == 511) bsum[blockIdx.y * 512 + blockIdx.x] = s[511];
}

__global__ void scan_bsums3(int* __restrict__ bsum, int B1, int B2, int B3) {
  int rel = blockIdx.x;
  int B = rel == 0 ? B1 : (rel == 1 ? B2 : B3);
  int* bs = bsum + rel * 512;
  __shared__ int s[512];
  int t = threadIdx.x;
  int v = (t < B) ? bs[t] : 0;
  s[t] = v;
  __syncthreads();
  for (int off = 1; off < 512; off <<= 1) {
    int x = s[t];
    int y = (t >= off) ? s[t - off] : 0;
    __syncthreads();
    s[t] = x + y;
    __syncthreads();
  }
  if (t < B) bs[t] = s[t] - v;  // exclusive
}

// add block offsets; seed pos[]; also emit float counts for rel2/rel3
__global__ void addoff3(int* __restrict__ o1, int* __restrict__ p1, int ns1,
                        int* __restrict__ o2, int* __restrict__ p2, int ns2,
                        int* __restrict__ o3, int* __restrict__ p3, int ns3,
                        const int* __restrict__ bsum,
                        const int* __restrict__ c2, float* __restrict__ f2,
                        const int* __restrict__ c3, float* __restrict__ f3) {
  int* o; int* p; int ns;
  switch (blockIdx.y) {
    case 0: o = o1; p = p1; ns = ns1; break;
    case 1: o = o2; p = p2; ns = ns2; break;
    default: o = o3; p = p3; ns = ns3; break;
  }
  int i = blockIdx.x * 512 + threadIdx.x;
  if (i < ns) {
    int v = o[i] + bsum[blockIdx.y * 512 + blockIdx.x];
    o[i] = v;
    p[i] = v;
    if (blockIdx.y == 1) f2[i] = (float)c2[i];
    else if (blockIdx.y == 2) f3[i] = (float)c3[i];
  }
}

// bucket: cites writes fused (src, weight-bits) int2; others write src only
__global__ void bucket3(
    const int* __restrict__ d1, const int* __restrict__ s1in,
    const float* __restrict__ w1in, int E1, int* __restrict__ p1,
    int2* __restrict__ swc,
    const int* __restrict__ d2, const int* __restrict__ s2in, int E2,
    int* __restrict__ p2, int* __restrict__ s2,
    const int* __restrict__ d3, const int* __restrict__ s3in, int E3,
    int* __restrict__ p3, int* __restrict__ s3) {
  int i = blockIdx.x * blockDim.x + threadIdx.x;
  int stride = gridDim.x * blockDim.x;
  int tot = E1 + E2 + E3;
  for (; i < tot; i += stride) {
    if (i < E1) {
      int p = atomicAdd(&p1[d1[i]], 1);
      int2 sw;
      sw.x = s1in[i];
      sw.y = __float_as_int(w1in[i]);
      swc[p] = sw;
    } else if (i < E1 + E2) {
      int k = i - E1;
      int p = atomicAdd(&p2[d2[k]], 1);
      s2[p] = s2in[k];
    } else {
      int k = i - E1 - E2;
      int p = atomicAdd(&p3[d3[k]], 1);
      s3[p] = s3in[k];
    }
  }
}

// ------------- feature aggregation (1 wave per dst row, all-bf16 gathers) -------------
__global__ void aggregate3(
    const unsigned short* __restrict__ Axp, const unsigned short* __restrict__ Axa,
    int Np, int Na,
    const int* __restrict__ off1, const int2* __restrict__ swc,
    const int* __restrict__ off2, const int* __restrict__ s2,
    const int* __restrict__ off3, const int* __restrict__ s3,
    unsigned short* __restrict__ agg_c, unsigned short* __restrict__ agg_w,
    unsigned short* __restrict__ agg_wr, float* __restrict__ wdeg) {
  int gw = (blockIdx.x * blockDim.x + threadIdx.x) >> 6;
  int lane = threadIdx.x & 63;
  if (gw < Np) {
    float4 vc = {0.f, 0.f, 0.f, 0.f};
    float4 vw = {0.f, 0.f, 0.f, 0.f};
    float wd = 0.f;
    int j1 = off1[gw], e1 = off1[gw + 1];
    int j2 = off2[gw], e2 = off2[gw + 1];
    // merged main loop: 2 cites + 2 writes gathers in flight together
    while (j1 + 2 <= e1 && j2 + 2 <= e2) {
      int2 pa = swc[j1], pb = swc[j1 + 1];
      float wa = __int_as_float(pa.y), wb = __int_as_float(pb.y);
      int sc = s2[j2], sd = s2[j2 + 1];
      ushort4 ma = *(const ushort4*)(Axp + ((size_t)pa.x << 8) + lane * 4);
      ushort4 mb = *(const ushort4*)(Axp + ((size_t)pb.x << 8) + lane * 4);
      ushort4 mc = *(const ushort4*)(Axa + ((size_t)sc << 8) + lane * 4);
      ushort4 md = *(const ushort4*)(Axa + ((size_t)sd << 8) + lane * 4);
      vc.x += wa * b2f(ma.x) + wb * b2f(mb.x);
      vc.y += wa * b2f(ma.y) + wb * b2f(mb.y);
      vc.z += wa * b2f(ma.z) + wb * b2f(mb.z);
      vc.w += wa * b2f(ma.w) + wb * b2f(mb.w);
      vw.x += b2f(mc.x) + b2f(md.x); vw.y += b2f(mc.y) + b2f(md.y);
      vw.z += b2f(mc.z) + b2f(md.z); vw.w += b2f(mc.w) + b2f(md.w);
      wd += wa + wb;
      j1 += 2; j2 += 2;
    }
    // 2-wide tails (2 independent gathers in flight)
    for (; j1 + 2 <= e1; j1 += 2) {
      int2 pa = swc[j1], pb = swc[j1 + 1];
      float wa = __int_as_float(pa.y), wb = __int_as_float(pb.y);
      ushort4 ma = *(const ushort4*)(Axp + ((size_t)pa.x << 8) + lane * 4);
      ushort4 mb = *(const ushort4*)(Axp + ((size_t)pb.x << 8) + lane * 4);
      vc.x += wa * b2f(ma.x) + wb * b2f(mb.x);
      vc.y += wa * b2f(ma.y) + wb * b2f(mb.y);
      vc.z += wa * b2f(ma.z) + wb * b2f(mb.z);
      vc.w += wa * b2f(ma.w) + wb * b2f(mb.w);
      wd += wa + wb;
    }
    if (j1 < e1) {
      int2 pa = swc[j1];
      float wa = __int_as_float(pa.y);
      ushort4 ma = *(const ushort4*)(Axp + ((size_t)pa.x << 8) + lane * 4);
      vc.x += wa * b2f(ma.x); vc.y += wa * b2f(ma.y);
      vc.z += wa * b2f(ma.z); vc.w += wa * b2f(ma.w);
      wd += wa;
    }
    for (; j2 + 2 <= e2; j2 += 2) {
      int sc = s2[j2], sd = s2[j2 + 1];
      ushort4 mc = *(const ushort4*)(Axa + ((size_t)sc << 8) + lane * 4);
      ushort4 md = *(const ushort4*)(Axa + ((size_t)sd << 8) + lane * 4);
      vw.x += b2f(mc.x) + b2f(md.x); vw.y += b2f(mc.y) + b2f(md.y);
      vw.z += b2f(mc.z) + b2f(md.z); vw.w += b2f(mc.w) + b2f(md.w);
    }
    if (j2 < e2) {
      int sc = s2[j2];
      ushort4 mc = *(const ushort4*)(Axa + ((size_t)sc << 8) + lane * 4);
      vw.x += b2f(mc.x); vw.y += b2f(mc.y);
      vw.z += b2f(mc.z); vw.w += b2f(mc.w);
    }
    ushort4 oc, ow;
    oc.x = f2b(vc.x); oc.y = f2b(vc.y); oc.z = f2b(vc.z); oc.w = f2b(vc.w);
    ow.x = f2b(vw.x); ow.y = f2b(vw.y); ow.z = f2b(vw.z); ow.w = f2b(vw.w);
    *(ushort4*)(agg_c + ((size_t)gw << 8) + lane * 4) = oc;
    *(ushort4*)(agg_w + ((size_t)gw << 8) + lane * 4) = ow;
    if (lane == 0) wdeg[gw] = wd;
  } else if (gw < Np + Na) {
    int r = gw - Np;
    float4 v = {0.f, 0.f, 0.f, 0.f};
    int j = off3[r], e = off3[r + 1];
    for (; j + 4 <= e; j += 4) {
      int sa = s3[j], sb = s3[j + 1], sc = s3[j + 2], sd = s3[j + 3];
      ushort4 ma = *(const ushort4*)(Axp + ((size_t)sa << 8) + lane * 4);
      ushort4 mb = *(const ushort4*)(Axp + ((size_t)sb << 8) + lane * 4);
      ushort4 mc = *(const ushort4*)(Axp + ((size_t)sc << 8) + lane * 4);
      ushort4 md = *(const ushort4*)(Axp + ((size_t)sd << 8) + lane * 4);
      v.x += b2f(ma.x) + b2f(mb.x) + b2f(mc.x) + b2f(md.x);
      v.y += b2f(ma.y) + b2f(mb.y) + b2f(mc.y) + b2f(md.y);
      v.z += b2f(ma.z) + b2f(mb.z) + b2f(mc.z) + b2f(md.z);
      v.w += b2f(ma.w) + b2f(mb.w) + b2f(mc.w) + b2f(md.w);
    }
    if (j + 2 <= e) {
      int sa = s3[j], sb = s3[j + 1];
      ushort4 ma = *(const ushort4*)(Axp + ((size_t)sa << 8) + lane * 4);
      ushort4 mb = *(const ushort4*)(Axp + ((size_t)sb << 8) + lane * 4);
      v.x += b2f(ma.x) + b2f(mb.x); v.y += b2f(ma.y) + b2f(mb.y);
      v.z += b2f(ma.z) + b2f(mb.z); v.w += b2f(ma.w) + b2f(mb.w);
      j += 2;
    }
    if (j < e) {
      int sa = s3[j];
      ushort4 ma = *(const ushort4*)(Axp + ((size_t)sa << 8) + lane * 4);
      v.x += b2f(ma.x); v.y += b2f(ma.y); v.z += b2f(ma.z); v.w += b2f(ma.w);
    }
    ushort4 o;
    o.x = f2b(v.x); o.y = f2b(v.y); o.z = f2b(v.z); o.w = f2b(v.w);
    *(ushort4*)(agg_wr + ((size_t)r << 8) + lane * 4) = o;
  }
}

// ------------- final GEMM: out = [A0|A1|A2] @ [B0;B1;B2] + row/col bias, ELU -------------
// 128x128 tile, BK=64, 4 waves (2x2), wave tile 64x64. All-bf16 A operands.
// No XCD swizzle (L3-fit working set; m160).
template <int NKT>
__device__ __forceinline__ void gemm_final_body(
    uint8_t* lds,
    const unsigned short* __restrict__ A0, const unsigned short* __restrict__ A1,
    const unsigned short* __restrict__ A2,
    const unsigned short* __restrict__ B0, const unsigned short* __restrict__ B1,
    const unsigned short* __restrict__ B2,
    const float* __restrict__ bias0, const float* __restrict__ bias1,
    const float* __restrict__ bias2,
    const float* __restrict__ rs1, const float* __restrict__ rs2,
    float* __restrict__ outp, int M, int row0, int n0, int tid) {
  uint8_t* ldsA = lds;            // 16 KB
  uint8_t* ldsB = lds + 16384;    // 16 KB
  const int lane = tid & 63;
  const int w = tid >> 6;
  const int wr = w >> 1, wc = w & 1;

  f32x4 acc[4][4] = {};

  for (int kt = 0; kt < NKT; ++kt) {
    const int kk = (kt & 3) << 6;
    const int sel = kt >> 2;
    const unsigned short* B = sel == 0 ? B0 : (sel == 1 ? B1 : B2);
    const unsigned short* A = sel == 0 ? A0 : (sel == 1 ? A1 : A2);
#pragma unroll
    for (int c = 0; c < 4; ++c) {
      int qq = c * 256 + tid;
      int row = qq >> 3, ch = qq & 7;
      int lch = ch ^ (row & 7);
      load_lds16(B + (size_t)(n0 + row) * 256 + kk + lch * 8, ldsB + qq * 16);
    }
#pragma unroll
    for (int c = 0; c < 4; ++c) {
      int qq = c * 256 + tid;
      int row = qq >> 3, ch = qq & 7;
      int lch = ch ^ (row & 7);
      int ar = row0 + row;
      if (ar >= M) ar = M - 1;
      load_lds16(A + (size_t)ar * 256 + kk + lch * 8, ldsA + qq * 16);
    }
    asm volatile("s_waitcnt vmcnt(0)" ::: "memory");
    __syncthreads();

#pragma unroll
    for (int s = 0; s < 2; ++s) {
      const int cbase = (s << 2) + (lane >> 4);
      short8 av[4];
#pragma unroll
      for (int m = 0; m < 4; ++m) {
        int rrow = wr * 64 + m * 16 + (lane & 15);
        av[m] = *(const short8*)(ldsA + rrow * 128 + ((cbase ^ (rrow & 7)) << 4));
      }
      short8 bv[4];
#pragma unroll
      for (int n = 0; n < 4; ++n) {
        int cc = wc * 64 + n * 16 + (lane & 15);
        bv[n] = *(const short8*)(ldsB + cc * 128 + ((cbase ^ (cc & 7)) << 4));
      }
#pragma unroll
      for (int m = 0; m < 4; ++m)
#pragma unroll
        for (int n = 0; n < 4; ++n)
          acc[m][n] = __builtin_amdgcn_mfma_f32_16x16x32_bf16(av[m], bv[n],
                                                              acc[m][n], 0, 0, 0);
    }
    __syncthreads();
  }

  // epilogue: combined bias + ELU, single f32 store
  float c0[4], c1v[4], c2v[4];
#pragma unroll
  for (int n = 0; n < 4; ++n) {
    int col = n0 + wc * 64 + n * 16 + (lane & 15);
    c0[n] = bias0[col];
    c1v[n] = bias1[col];
    c2v[n] = bias2 ? bias2[col] : 0.f;
  }
#pragma unroll
  for (int m = 0; m < 4; ++m) {
#pragma unroll
    for (int j = 0; j < 4; ++j) {
      int row = row0 + wr * 64 + m * 16 + (lane >> 4) * 4 + j;
      if (row < M) {
        float r1 = rs1[row];
        float r2 = rs2 ? rs2[row] : 0.f;
#pragma unroll
        for (int n = 0; n < 4; ++n) {
          int col = n0 + wc * 64 + n * 16 + (lane & 15);
          float v = acc[m][n][j] + c0[n] + r1 * c1v[n] + r2 * c2v[n];
          outp[(size_t)row * 256 + col] = elu1(v);
        }
      }
    }
  }
}

__global__ __launch_bounds__(256, 3) void gemm_final(
    const unsigned short* __restrict__ Axp, const unsigned short* __restrict__ Axa,
    const unsigned short* __restrict__ agg_c, const unsigned short* __restrict__ agg_w,
    const unsigned short* __restrict__ agg_wr,
    const unsigned short* __restrict__ WT_sp, const unsigned short* __restrict__ WT_c,
    const unsigned short* __restrict__ WT_w, const unsigned short* __restrict__ WT_sa,
    const unsigned short* __restrict__ WT_wr,
    const float* __restrict__ b_sp, const float* __restrict__ b_c,
    const float* __restrict__ b_w, const float* __restrict__ b_sa,
    const float* __restrict__ b_wr,
    const float* __restrict__ wdeg, const float* __restrict__ cntw_f,
    const float* __restrict__ cntwr_f,
    float* __restrict__ out_p, float* __restrict__ out_a,
    int Mp, int Ma, int nwgp, int nwg) {
  __shared__ uint8_t lds[32768];
  const int wgid = blockIdx.x;  // no XCD swizzle: working set is L3-fit
  const int tid = threadIdx.x;
  if (wgid < nwgp) {
    gemm_final_body<12>(lds, Axp, agg_c, agg_w,
                        WT_sp, WT_c, WT_w,
                        b_sp, b_c, b_w, wdeg, cntw_f,
                        out_p, Mp, (wgid >> 1) * 128, (wgid & 1) * 128, tid);
  } else {
    int w2 = wgid - nwgp;
    gemm_final_body<8>(lds, Axa, agg_wr, nullptr,
                       WT_sa, WT_wr, nullptr,
                       b_sa, b_wr, nullptr, cntwr_f, nullptr,
                       out_a, Ma, (w2 >> 1) * 128, (w2 & 1) * 128, tid);
  }
}

extern "C" void kernel_launch(void* const* d_in, const int* in_sizes, int n_in,
                              void* d_out, int out_size, void* d_ws, size_t ws_size,
                              hipStream_t stream) {
  const float* x_p = (const float*)d_in[0];
  const float* x_a = (const float*)d_in[1];
  const int* c_src = (const int*)d_in[2];
  const int* c_dst = (const int*)d_in[3];
  const float* c_w = (const float*)d_in[4];
  const int* w_src = (const int*)d_in[5];
  const int* w_dst = (const int*)d_in[6];
  const int* wr_src = (const int*)d_in[7];
  const int* wr_dst = (const int*)d_in[8];
  const float* W_sp = (const float*)d_in[9];
  const float* b_sp = (const float*)d_in[10];
  const float* W_sa = (const float*)d_in[11];
  const float* b_sa = (const float*)d_in[12];
  const float* W_c  = (const float*)d_in[13];
  const float* b_c  = (const float*)d_in[14];
  const float* W_w  = (const float*)d_in[15];
  const float* b_w  = (const float*)d_in[16];
  const float* W_wr = (const float*)d_in[17];
  const float* b_wr = (const float*)d_in[18];

  const int Mp = in_sizes[0] / 256;
  const int Ma = in_sizes[1] / 256;
  const int Ec = in_sizes[2], Ew = in_sizes[5], Ewr = in_sizes[7];

  // ---- workspace bump allocator (256B aligned); total ~218 MB ----
  size_t wo = 0;
  auto alloc = [&](size_t bytes) -> void* {
    void* p = (char*)d_ws + wo;
    wo += (bytes + 255) & ~(size_t)255;
    return p;
  };
  unsigned short* Axp    = (unsigned short*)alloc((size_t)Mp * 512);  // bf16 x_p
  unsigned short* Axa    = (unsigned short*)alloc((size_t)Ma * 512);  // bf16 x_a
  unsigned short* agg_c  = (unsigned short*)alloc((size_t)Mp * 512);
  unsigned short* agg_w  = (unsigned short*)alloc((size_t)Mp * 512);
  unsigned short* agg_wr = (unsigned short*)alloc((size_t)Ma * 512);
  unsigned short* WT_sp = (unsigned short*)alloc(131072);
  unsigned short* WT_sa = (unsigned short*)alloc(131072);
  unsigned short* WT_c  = (unsigned short*)alloc(131072);
  unsigned short* WT_w  = (unsigned short*)alloc(131072);
  unsigned short* WT_wr = (unsigned short*)alloc(131072);
  int* cnt_c  = (int*)alloc((size_t)((Mp + 1) + (Mp + 1) + (Ma + 1)) * 4);
  int* cnt_w  = cnt_c + (Mp + 1);
  int* cnt_wr = cnt_w + (Mp + 1);
  size_t cnt_bytes = (size_t)((Mp + 1) + (Mp + 1) + (Ma + 1)) * 4;
  int* off_c  = (int*)alloc((size_t)(Mp + 1) * 4);
  int* pos_c  = (int*)alloc((size_t)(Mp + 1) * 4);
  int* off_w  = (int*)alloc((size_t)(Mp + 1) * 4);
  int* pos_w  = (int*)alloc((size_t)(Mp + 1) * 4);
  int* off_wr = (int*)alloc((size_t)(Ma + 1) * 4);
  int* pos_wr = (int*)alloc((size_t)(Ma + 1) * 4);
  int2* swc    = (int2*)alloc((size_t)Ec * 8);     // fused (src, w-bits) for cites
  int* srcs_w  = (int*)alloc((size_t)Ew * 4);
  int* srcs_wr = (int*)alloc((size_t)Ewr * 4);
  int* bsum = (int*)alloc(3 * 512 * 4);
  float* wdeg = (float*)alloc((size_t)Mp * 4);
  float* cntw_f = (float*)alloc((size_t)(Mp + 1) * 4);
  float* cntwr_f = (float*)alloc((size_t)(Ma + 1) * 4);

  float* out_p = (float*)d_out;
  float* out_a = (float*)d_out + (size_t)Mp * 256;

  // ---- prep (1 dispatch): cvt (x_p + x_a) || transposes || hist ----
  hipMemsetAsync(cnt_c, 0, cnt_bytes, stream);
  prep_all<<<NB_CVT + NB_T + NB_H, 256, 0, stream>>>(
      (const float4*)x_p, (ushort4*)Axp, Mp * 64,
      (const float4*)x_a, (ushort4*)Axa, Ma * 64,
      W_sp, W_sa, W_c, W_w, W_wr,
      WT_sp, WT_sa, WT_c, WT_w, WT_wr,
      c_dst, Ec, cnt_c, w_dst, Ew, cnt_w, wr_dst, Ewr, cnt_wr);

  // ---- CSR scans + bucket (cnt->float folded into addoff3) ----
  const int ns1 = Mp + 1, ns2 = Mp + 1, ns3 = Ma + 1;
  const int B1 = (ns1 + 511) / 512, B2 = (ns2 + 511) / 512, B3 = (ns3 + 511) / 512;
  const int Bmax = B1 > B2 ? (B1 > B3 ? B1 : B3) : (B2 > B3 ? B2 : B3);
  {
    dim3 g(Bmax, 3);
    scan512_3<<<g, 512, 0, stream>>>(cnt_c, off_c, ns1, cnt_w, off_w, ns2,
                                     cnt_wr, off_wr, ns3, bsum);
    scan_bsums3<<<3, 512, 0, stream>>>(bsum, B1, B2, B3);
    addoff3<<<g, 512, 0, stream>>>(off_c, pos_c, ns1, off_w, pos_w, ns2,
                                   off_wr, pos_wr, ns3, bsum,
                                   cnt_w, cntw_f, cnt_wr, cntwr_f);
  }
  bucket3<<<256, 256, 0, stream>>>(c_dst, c_src, c_w, Ec, pos_c, swc,
                                   w_dst, w_src, Ew, pos_w, srcs_w,
                                   wr_dst, wr_src, Ewr, pos_wr, srcs_wr);

  // ---- feature aggregation (all-bf16 gathers, fused cites src+weight) ----
  {
    int totalWaves = Mp + Ma;
    aggregate3<<<(totalWaves + 3) / 4, 256, 0, stream>>>(
        Axp, Axa, Mp, Ma,
        off_c, swc, off_w, srcs_w, off_wr, srcs_wr,
        agg_c, agg_w, agg_wr, wdeg);
  }

  // ---- final fused GEMM (K=768 paper / K=512 author) + bias + ELU ----
  {
    const int nsp = (Mp + 127) / 128, nsa = (Ma + 127) / 128;
    const int nwgp = nsp * 2, nwga = nsa * 2;
    gemm_final<<<nwgp + nwga, 256, 0, stream>>>(
        Axp, Axa, agg_c, agg_w, agg_wr,
        WT_sp, WT_c, WT_w, WT_sa, WT_wr,
        b_sp, b_c, b_w, b_sa, b_wr,
        wdeg, cntw_f, cntwr_f,
        out_p, out_a, Mp, Ma, nwgp, nwgp + nwga);
  }
}